// Round 1
// baseline (960.216 us; speedup 1.0000x reference)
//
#include <hip/hip_runtime.h>
#include <hip/hip_bf16.h>
#include <math.h>

#define A_TOTAL 159882
#define NGT 20

// ---- level geometry: p6(13) p5(25) p4(50) p3(100) p2(200), 3 anchors/pos ----
// cumulative anchor offsets: 0, 507, 2382, 9882, 39882, 159882

__device__ __forceinline__ float iou_one(float ax1, float ay1, float ax2, float ay2,
                                         float gx1, float gy1, float gx2, float gy2) {
    float a1 = (ax2 - ax1) * (ay2 - ay1);
    float a2 = (gx2 - gx1) * (gy2 - gy1);
    float ltx = fmaxf(ax1, gx1), lty = fmaxf(ay1, gy1);
    float rbx = fminf(ax2, gx2), rby = fminf(ay2, gy2);
    float w = fmaxf(rbx - ltx, 0.f), h = fmaxf(rby - lty, 0.f);
    float inter = w * h;
    return inter / (a1 + a2 - inter);
}

__global__ void k_init(unsigned int* best, int* pos_total, int* sel_count, float* out) {
    int t = threadIdx.x;
    if (t < 2 * NGT) best[t] = 0u;
    if (t < 2) { pos_total[t] = 0; sel_count[t] = 0; out[t] = 0.f; }
}

// pass 1: best_per_gt via wave-reduced bitwise atomicMax (IoU >= 0)
__global__ void k_best(const float* __restrict__ anchors, const float* __restrict__ gt,
                       unsigned int* best) {
    int a = blockIdx.x * blockDim.x + threadIdx.x;
    int img = blockIdx.y;
    bool act = (a < A_TOTAL);
    float ax1 = 0.f, ay1 = 0.f, ax2 = 1.f, ay2 = 1.f;
    if (act) {
        ax1 = anchors[a * 4 + 0]; ay1 = anchors[a * 4 + 1];
        ax2 = anchors[a * 4 + 2]; ay2 = anchors[a * 4 + 3];
    }
    int lane = threadIdx.x & 63;
    for (int g = 0; g < NGT; g++) {
        const float* gp = gt + (size_t)(img * NGT + g) * 4;
        float v = act ? iou_one(ax1, ay1, ax2, ay2, gp[0], gp[1], gp[2], gp[3]) : 0.f;
        unsigned int bits = __float_as_uint(v);
        #pragma unroll
        for (int o = 32; o > 0; o >>= 1) {
            unsigned int ob = __shfl_down(bits, o);
            bits = bits > ob ? bits : ob;
        }
        if (lane == 0) atomicMax(&best[img * NGT + g], bits);
    }
}

// pass 2: labels + matched gt, packed (code<<5)|matched ; count positives
__global__ void k_label(const float* __restrict__ anchors, const float* __restrict__ gt,
                        const unsigned int* __restrict__ best,
                        unsigned char* packed, int* pos_total) {
    int a = blockIdx.x * blockDim.x + threadIdx.x;
    if (a >= A_TOTAL) return;
    int img = blockIdx.y;
    float ax1 = anchors[a * 4 + 0], ay1 = anchors[a * 4 + 1];
    float ax2 = anchors[a * 4 + 2], ay2 = anchors[a * 4 + 3];
    float mval = -1.f; int arg = 0; bool lq = false;
    for (int g = 0; g < NGT; g++) {
        const float* gp = gt + (size_t)(img * NGT + g) * 4;
        float v = iou_one(ax1, ay1, ax2, ay2, gp[0], gp[1], gp[2], gp[3]);
        if (v > mval) { mval = v; arg = g; }
        if (__float_as_uint(v) == best[img * NGT + g] && v > 0.f) lq = true;
    }
    int code;
    if (lq || mval >= 0.7f) code = 1;
    else if (mval < 0.3f)   code = 0;
    else                    code = 2;   // ignore
    if (code == 1) atomicAdd(&pos_total[img], 1);
    packed[(size_t)img * A_TOTAL + a] = (unsigned char)((code << 5) | arg);
}

// pass 3: deterministic subsample via ordered prefix scan; compact selected
__global__ void k_scan(const unsigned char* __restrict__ packed,
                       const int* __restrict__ pos_total,
                       int* sel, int* sel_count) {
    const int img = blockIdx.x;
    const unsigned char* lab = packed + (size_t)img * A_TOTAL;
    const int npos = min(pos_total[img], 128);
    const int cap_neg = 256 - npos;
    const int tid = threadIdx.x;            // 1024 threads
    const int lane = tid & 63, wid = tid >> 6;
    __shared__ int wsum[16];
    __shared__ int chunk_tot;
    int base_p = 0, base_n = 0;
    for (int start = 0; start < A_TOTAL; start += 1024 * 16) {
        int i0 = start + tid * 16;
        int tp = 0, tn = 0;
        unsigned char lbs[16];
        #pragma unroll
        for (int k = 0; k < 16; k++) {
            int i = i0 + k;
            unsigned char b = (i < A_TOTAL) ? lab[i] : (unsigned char)(2 << 5);
            lbs[k] = b;
            int code = b >> 5;
            tp += (code == 1); tn += (code == 0);
        }
        int v = (tp << 16) | tn;
        // wave inclusive scan
        #pragma unroll
        for (int off = 1; off < 64; off <<= 1) {
            int u = __shfl_up(v, off);
            if (lane >= off) v += u;
        }
        if (lane == 63) wsum[wid] = v;
        __syncthreads();
        if (wid == 0) {
            int w = (lane < 16) ? wsum[lane] : 0;
            #pragma unroll
            for (int off = 1; off < 16; off <<= 1) {
                int u = __shfl_up(w, off);
                if (lane >= off) w += u;
            }
            if (lane < 16) wsum[lane] = w;     // inclusive wave prefix
            if (lane == 15) chunk_tot = w;
        }
        __syncthreads();
        int wave_excl = (wid > 0) ? wsum[wid - 1] : 0;
        int excl = v - ((tp << 16) | tn) + wave_excl;   // fieldwise, no borrow
        int run_p = base_p + (excl >> 16);
        int run_n = base_n + (excl & 0xFFFF);
        for (int k = 0; k < 16; k++) {
            int i = i0 + k;
            if (i >= A_TOTAL) break;
            int code = lbs[k] >> 5;
            if (code == 1) {
                run_p++;
                if (run_p <= 128) {
                    int s = atomicAdd(&sel_count[img], 1);
                    sel[img * 256 + s] = i | (1 << 30);
                }
            } else if (code == 0) {
                run_n++;
                if (run_n <= cap_neg) {
                    int s = atomicAdd(&sel_count[img], 1);
                    sel[img * 256 + s] = i;
                }
            }
        }
        int ct = chunk_tot;
        base_p += (ct >> 16); base_n += (ct & 0xFFFF);
        __syncthreads();
    }
}

// pass 4: sparse conv eval at selected anchors + loss accumulation
__global__ __launch_bounds__(256) void k_eval(
    const float* __restrict__ f0, const float* __restrict__ f1,
    const float* __restrict__ f2, const float* __restrict__ f3,
    const float* __restrict__ f4,
    const float* __restrict__ anchors, const float* __restrict__ gt,
    const float* __restrict__ w_in, const float* __restrict__ b_in,
    const float* __restrict__ w_obj, const float* __restrict__ b_obj,
    const float* __restrict__ w_del, const float* __restrict__ b_del,
    const unsigned char* __restrict__ packed,
    const int* __restrict__ sel, const int* __restrict__ sel_count,
    float* out) {
    const int img = blockIdx.x >> 8;
    const int slot = blockIdx.x & 255;
    if (slot >= sel_count[img]) return;
    const int e = sel[img * 256 + slot];
    const int is_pos = (e >> 30) & 1;
    const int a = e & 0x3FFFFFFF;
    // decode level / spatial position / anchor id
    int off, W;
    if      (a < 507)   { off = 0;     W = 13;  }
    else if (a < 2382)  { off = 507;   W = 25;  }
    else if (a < 9882)  { off = 2382;  W = 50;  }
    else if (a < 39882) { off = 9882;  W = 100; }
    else                { off = 39882; W = 200; }
    const int rel = a - off;
    const int aid = rel % 3;
    const int pos = rel / 3;
    const int y = pos / W, x = pos % W;
    const float* fm = (W == 13) ? f0 : (W == 25) ? f1 : (W == 50) ? f2 : (W == 100) ? f3 : f4;
    const float* fimg = fm + (size_t)img * 256 * W * W;

    __shared__ __align__(16) float patch[2304];   // [ci][3][3]
    __shared__ float red[5][4];
    const int c = threadIdx.x;

    // stage 3x3 zero-padded patch of this position (channel c)
    {
        const float* ch = fimg + (size_t)c * W * W;
        #pragma unroll
        for (int ky = 0; ky < 3; ky++)
            #pragma unroll
            for (int kx = 0; kx < 3; kx++) {
                int yy = y + ky - 1, xx = x + kx - 1;
                float v = (yy >= 0 && yy < W && xx >= 0 && xx < W) ? ch[yy * W + xx] : 0.f;
                patch[c * 9 + ky * 3 + kx] = v;
            }
    }
    __syncthreads();

    // x_feat[c] = relu(conv3x3): 2304-term dot, float4-vectorized
    float acc = b_in[c];
    const float4* wr = (const float4*)(w_in + (size_t)c * 2304);
    const float4* p4 = (const float4*)patch;
    #pragma unroll 8
    for (int i = 0; i < 576; i++) {
        float4 w = wr[i], p = p4[i];
        acc += w.x * p.x + w.y * p.y + w.z * p.z + w.w * p.w;
    }
    float xf = fmaxf(acc, 0.f);

    // 5 block-wide dot products: logit + 4 deltas
    float part[5];
    part[0] = xf * w_obj[aid * 256 + c];
    #pragma unroll
    for (int j = 0; j < 4; j++) part[1 + j] = xf * w_del[(aid * 4 + j) * 256 + c];
    const int lane = c & 63, wid = c >> 6;
    #pragma unroll
    for (int o = 32; o > 0; o >>= 1)
        #pragma unroll
        for (int j = 0; j < 5; j++) part[j] += __shfl_down(part[j], o);
    if (lane == 0)
        for (int j = 0; j < 5; j++) red[j][wid] = part[j];
    __syncthreads();

    if (c == 0) {
        float logit = red[0][0] + red[0][1] + red[0][2] + red[0][3] + b_obj[aid];
        float tgt = is_pos ? 1.f : 0.f;
        float bce = fmaxf(logit, 0.f) - logit * tgt + log1pf(expf(-fabsf(logit)));
        atomicAdd(&out[0], 0.5f * bce);
        if (is_pos) {
            float d[4];
            #pragma unroll
            for (int j = 0; j < 4; j++)
                d[j] = red[1 + j][0] + red[1 + j][1] + red[1 + j][2] + red[1 + j][3] + b_del[aid * 4 + j];
            int m = packed[(size_t)img * A_TOTAL + a] & 31;
            const float* s = anchors + (size_t)a * 4;
            const float* t = gt + (size_t)(img * NGT + m) * 4;
            float sw = s[2] - s[0], sh = s[3] - s[1];
            float scx = s[0] + 0.5f * sw, scy = s[1] + 0.5f * sh;
            float tw = t[2] - t[0], th = t[3] - t[1];
            float tcx = t[0] + 0.5f * tw, tcy = t[1] + 0.5f * th;
            float g0 = (tcx - scx) / sw, g1 = (tcy - scy) / sh;
            float g2 = logf(tw / sw),    g3 = logf(th / sh);
            float l1 = fabsf(d[0] - g0) + fabsf(d[1] - g1) + fabsf(d[2] - g2) + fabsf(d[3] - g3);
            atomicAdd(&out[1], 0.5f * l1);
        }
    }
}

extern "C" void kernel_launch(void* const* d_in, const int* in_sizes, int n_in,
                              void* d_out, int out_size, void* d_ws, size_t ws_size,
                              hipStream_t stream) {
    const float* f_p6 = (const float*)d_in[0];
    const float* f_p5 = (const float*)d_in[1];
    const float* f_p4 = (const float*)d_in[2];
    const float* f_p3 = (const float*)d_in[3];
    const float* f_p2 = (const float*)d_in[4];
    const float* anchors = (const float*)d_in[5];
    const float* gt      = (const float*)d_in[6];
    const float* w_in  = (const float*)d_in[7];
    const float* b_in  = (const float*)d_in[8];
    const float* w_obj = (const float*)d_in[9];
    const float* b_obj = (const float*)d_in[10];
    const float* w_del = (const float*)d_in[11];
    const float* b_del = (const float*)d_in[12];

    // workspace layout (needs ~323 KB)
    char* ws = (char*)d_ws;
    unsigned int* best = (unsigned int*)(ws + 0);      // 40 * 4 = 160 B
    int* pos_total     = (int*)(ws + 160);             // 8 B
    int* sel_count     = (int*)(ws + 168);             // 8 B
    int* sel           = (int*)(ws + 192);             // 512 * 4 = 2048 B
    unsigned char* packed = (unsigned char*)(ws + 2304); // 2 * A_TOTAL bytes

    float* out = (float*)d_out;

    k_init<<<1, 64, 0, stream>>>(best, pos_total, sel_count, out);
    dim3 g1((A_TOTAL + 255) / 256, 2);
    k_best<<<g1, 256, 0, stream>>>(anchors, gt, best);
    k_label<<<g1, 256, 0, stream>>>(anchors, gt, best, packed, pos_total);
    k_scan<<<2, 1024, 0, stream>>>(packed, pos_total, sel, sel_count);
    k_eval<<<512, 256, 0, stream>>>(f_p6, f_p5, f_p4, f_p3, f_p2,
                                    anchors, gt, w_in, b_in, w_obj, b_obj,
                                    w_del, b_del, packed, sel, sel_count, out);
}

// Round 2
// 276.522 us; speedup vs baseline: 3.4725x; 3.4725x over previous
//
#include <hip/hip_runtime.h>
#include <hip/hip_bf16.h>
#include <math.h>

#define A_TOTAL 159882
#define NGT 20

// level geometry: p6(13) p5(25) p4(50) p3(100) p2(200), 3 anchors/pos
// cumulative anchor offsets: 0, 507, 2382, 9882, 39882, 159882

__device__ __forceinline__ float iou_one(float ax1, float ay1, float ax2, float ay2,
                                         float gx1, float gy1, float gx2, float gy2) {
    float a1 = (ax2 - ax1) * (ay2 - ay1);
    float a2 = (gx2 - gx1) * (gy2 - gy1);
    float ltx = fmaxf(ax1, gx1), lty = fmaxf(ay1, gy1);
    float rbx = fminf(ax2, gx2), rby = fminf(ay2, gy2);
    float w = fmaxf(rbx - ltx, 0.f), h = fmaxf(rby - lty, 0.f);
    float inter = w * h;
    return inter / (a1 + a2 - inter);
}

__device__ __forceinline__ void decode_anchor(int a, int& W, int& aid, int& y, int& x, int& lvl) {
    int off;
    if      (a < 507)   { off = 0;     W = 13;  lvl = 0; }
    else if (a < 2382)  { off = 507;   W = 25;  lvl = 1; }
    else if (a < 9882)  { off = 2382;  W = 50;  lvl = 2; }
    else if (a < 39882) { off = 9882;  W = 100; lvl = 3; }
    else                { off = 39882; W = 200; lvl = 4; }
    int rel = a - off;
    aid = rel % 3;
    int pos = rel / 3;
    y = pos / W; x = pos % W;
}

__global__ void k_init(unsigned int* best, int* pos_total, int* sel_count, float* out) {
    int t = threadIdx.x;
    if (t < 2 * NGT) best[t] = 0u;
    if (t < 2) { pos_total[t] = 0; sel_count[t] = 0; out[t] = 0.f; }
}

// pass 1: best_per_gt. Register-resident running max per thread over ~10 anchors,
// wave shfl reduce + LDS block reduce -> only 20 atomics per block.
__global__ void k_best(const float* __restrict__ anchors, const float* __restrict__ gt,
                       unsigned int* best) {
    const int img = blockIdx.y;
    __shared__ float sgt[NGT * 4];
    __shared__ float sred[4][NGT];
    const int tid = threadIdx.x;
    if (tid < NGT * 4) sgt[tid] = gt[img * NGT * 4 + tid];
    __syncthreads();
    float vmax[NGT];
    #pragma unroll
    for (int g = 0; g < NGT; g++) vmax[g] = 0.f;
    const int stride = gridDim.x * blockDim.x;
    for (int a = blockIdx.x * blockDim.x + tid; a < A_TOTAL; a += stride) {
        float4 ab = ((const float4*)anchors)[a];
        #pragma unroll
        for (int g = 0; g < NGT; g++) {
            float v = iou_one(ab.x, ab.y, ab.z, ab.w,
                              sgt[g * 4], sgt[g * 4 + 1], sgt[g * 4 + 2], sgt[g * 4 + 3]);
            vmax[g] = fmaxf(vmax[g], v);
        }
    }
    const int lane = tid & 63, wid = tid >> 6;
    #pragma unroll
    for (int g = 0; g < NGT; g++) {
        float v = vmax[g];
        #pragma unroll
        for (int o = 32; o > 0; o >>= 1) v = fmaxf(v, __shfl_down(v, o));
        if (lane == 0) sred[wid][g] = v;
    }
    __syncthreads();
    if (tid < NGT) {
        float v = fmaxf(fmaxf(sred[0][tid], sred[1][tid]),
                        fmaxf(sred[2][tid], sred[3][tid]));
        atomicMax(&best[img * NGT + tid], __float_as_uint(v));
    }
}

// pass 2: labels + matched gt, packed (code<<5)|matched ; count positives
__global__ void k_label(const float* __restrict__ anchors, const float* __restrict__ gt,
                        const unsigned int* __restrict__ best,
                        unsigned char* packed, int* pos_total) {
    const int img = blockIdx.y;
    __shared__ float sgt[NGT * 4];
    __shared__ unsigned int sbest[NGT];
    const int tid = threadIdx.x;
    if (tid < NGT * 4) sgt[tid] = gt[img * NGT * 4 + tid];
    if (tid < NGT) sbest[tid] = best[img * NGT + tid];
    __syncthreads();
    int a = blockIdx.x * blockDim.x + tid;
    if (a >= A_TOTAL) return;
    float4 ab = ((const float4*)anchors)[a];
    float mval = -1.f; int arg = 0; bool lq = false;
    #pragma unroll
    for (int g = 0; g < NGT; g++) {
        float v = iou_one(ab.x, ab.y, ab.z, ab.w,
                          sgt[g * 4], sgt[g * 4 + 1], sgt[g * 4 + 2], sgt[g * 4 + 3]);
        if (v > mval) { mval = v; arg = g; }
        if (__float_as_uint(v) == sbest[g] && v > 0.f) lq = true;
    }
    int code;
    if (lq || mval >= 0.7f) code = 1;
    else if (mval < 0.3f)   code = 0;
    else                    code = 2;   // ignore
    if (code == 1) atomicAdd(&pos_total[img], 1);
    packed[(size_t)img * A_TOTAL + a] = (unsigned char)((code << 5) | arg);
}

// pass 3: deterministic subsample via ordered prefix scan; compact selected
__global__ void k_scan(const unsigned char* __restrict__ packed,
                       const int* __restrict__ pos_total,
                       int* sel, int* sel_count) {
    const int img = blockIdx.x;
    const unsigned char* lab = packed + (size_t)img * A_TOTAL;
    const int npos = min(pos_total[img], 128);
    const int cap_neg = 256 - npos;
    const int tid = threadIdx.x;            // 1024 threads
    const int lane = tid & 63, wid = tid >> 6;
    __shared__ int wsum[16];
    __shared__ int chunk_tot;
    int base_p = 0, base_n = 0;
    for (int start = 0; start < A_TOTAL; start += 1024 * 16) {
        int i0 = start + tid * 16;
        int tp = 0, tn = 0;
        unsigned char lbs[16];
        #pragma unroll
        for (int k = 0; k < 16; k++) {
            int i = i0 + k;
            unsigned char b = (i < A_TOTAL) ? lab[i] : (unsigned char)(2 << 5);
            lbs[k] = b;
            int code = b >> 5;
            tp += (code == 1); tn += (code == 0);
        }
        int v = (tp << 16) | tn;
        #pragma unroll
        for (int off = 1; off < 64; off <<= 1) {
            int u = __shfl_up(v, off);
            if (lane >= off) v += u;
        }
        if (lane == 63) wsum[wid] = v;
        __syncthreads();
        if (wid == 0) {
            int w = (lane < 16) ? wsum[lane] : 0;
            #pragma unroll
            for (int off = 1; off < 16; off <<= 1) {
                int u = __shfl_up(w, off);
                if (lane >= off) w += u;
            }
            if (lane < 16) wsum[lane] = w;
            if (lane == 15) chunk_tot = w;
        }
        __syncthreads();
        int wave_excl = (wid > 0) ? wsum[wid - 1] : 0;
        int excl = v - ((tp << 16) | tn) + wave_excl;
        int run_p = base_p + (excl >> 16);
        int run_n = base_n + (excl & 0xFFFF);
        for (int k = 0; k < 16; k++) {
            int i = i0 + k;
            if (i >= A_TOTAL) break;
            int code = lbs[k] >> 5;
            if (code == 1) {
                run_p++;
                if (run_p <= 128) {
                    int s = atomicAdd(&sel_count[img], 1);
                    sel[img * 256 + s] = i | (1 << 30);
                }
            } else if (code == 0) {
                run_n++;
                if (run_n <= cap_neg) {
                    int s = atomicAdd(&sel_count[img], 1);
                    sel[img * 256 + s] = i;
                }
            }
        }
        int ct = chunk_tot;
        base_p += (ct >> 16); base_n += (ct & 0xFFFF);
        __syncthreads();
    }
}

// pass 4: sparse conv eval, 4 anchors per block (w_in float4 reused 4x)
__global__ __launch_bounds__(256) void k_eval(
    const float* __restrict__ f0, const float* __restrict__ f1,
    const float* __restrict__ f2, const float* __restrict__ f3,
    const float* __restrict__ f4,
    const float* __restrict__ anchors, const float* __restrict__ gt,
    const float* __restrict__ w_in, const float* __restrict__ b_in,
    const float* __restrict__ w_obj, const float* __restrict__ b_obj,
    const float* __restrict__ w_del, const float* __restrict__ b_del,
    const unsigned char* __restrict__ packed,
    const int* __restrict__ sel, const int* __restrict__ sel_count,
    float* out) {
    const int img = blockIdx.x >> 6;           // 64 blocks per image
    const int slot0 = (blockIdx.x & 63) * 4;
    const int nsel = sel_count[img];
    if (slot0 >= nsel) return;

    __shared__ __align__(16) float patch[4][2304];
    __shared__ float red[4][5][4];
    __shared__ float lsum[2];
    const int c = threadIdx.x;
    if (c < 2) lsum[c] = 0.f;

    bool actv[4]; int av[4], aidv[4], isposv[4];
    #pragma unroll
    for (int aa = 0; aa < 4; aa++) {
        int slot = slot0 + aa;
        bool act = slot < nsel;
        actv[aa] = act;
        int e = act ? sel[img * 256 + slot] : 0;
        isposv[aa] = (e >> 30) & 1;
        int a = e & 0x3FFFFFFF;
        av[aa] = a;
        int W, aid, y, x, lvl;
        decode_anchor(a, W, aid, y, x, lvl);
        aidv[aa] = aid;
        const float* fm = lvl == 0 ? f0 : lvl == 1 ? f1 : lvl == 2 ? f2 : lvl == 3 ? f3 : f4;
        const float* ch = fm + ((size_t)img * 256 + c) * W * W;
        #pragma unroll
        for (int ky = 0; ky < 3; ky++)
            #pragma unroll
            for (int kx = 0; kx < 3; kx++) {
                int yy = y + ky - 1, xx = x + kx - 1;
                float v = (act && yy >= 0 && yy < W && xx >= 0 && xx < W) ? ch[yy * W + xx] : 0.f;
                patch[aa][c * 9 + ky * 3 + kx] = v;
            }
    }
    __syncthreads();

    const float bi = b_in[c];
    float acc0 = bi, acc1 = bi, acc2 = bi, acc3 = bi;
    const float4* wr = (const float4*)(w_in + (size_t)c * 2304);
    const float4* p0 = (const float4*)patch[0];
    const float4* p1 = (const float4*)patch[1];
    const float4* p2 = (const float4*)patch[2];
    const float4* p3 = (const float4*)patch[3];
    #pragma unroll 4
    for (int i = 0; i < 576; i++) {
        float4 w = wr[i];
        float4 q;
        q = p0[i]; acc0 += w.x * q.x + w.y * q.y + w.z * q.z + w.w * q.w;
        q = p1[i]; acc1 += w.x * q.x + w.y * q.y + w.z * q.z + w.w * q.w;
        q = p2[i]; acc2 += w.x * q.x + w.y * q.y + w.z * q.z + w.w * q.w;
        q = p3[i]; acc3 += w.x * q.x + w.y * q.y + w.z * q.z + w.w * q.w;
    }
    float xf[4] = { fmaxf(acc0, 0.f), fmaxf(acc1, 0.f), fmaxf(acc2, 0.f), fmaxf(acc3, 0.f) };

    // 20 block-wide dot products: (logit + 4 deltas) x 4 anchors
    float part[4][5];
    #pragma unroll
    for (int aa = 0; aa < 4; aa++) {
        part[aa][0] = xf[aa] * w_obj[aidv[aa] * 256 + c];
        #pragma unroll
        for (int j = 0; j < 4; j++)
            part[aa][1 + j] = xf[aa] * w_del[(aidv[aa] * 4 + j) * 256 + c];
    }
    const int lane = c & 63, wid = c >> 6;
    #pragma unroll
    for (int o = 32; o > 0; o >>= 1)
        #pragma unroll
        for (int aa = 0; aa < 4; aa++)
            #pragma unroll
            for (int j = 0; j < 5; j++)
                part[aa][j] += __shfl_down(part[aa][j], o);
    if (lane == 0)
        #pragma unroll
        for (int aa = 0; aa < 4; aa++)
            #pragma unroll
            for (int j = 0; j < 5; j++)
                red[aa][j][wid] = part[aa][j];
    __syncthreads();

    if (c < 4 && actv[c]) {
        const int aa = c;
        float logit = red[aa][0][0] + red[aa][0][1] + red[aa][0][2] + red[aa][0][3] + b_obj[aidv[aa]];
        float tgt = isposv[aa] ? 1.f : 0.f;
        float bce = fmaxf(logit, 0.f) - logit * tgt + log1pf(expf(-fabsf(logit)));
        atomicAdd(&lsum[0], bce);
        if (isposv[aa]) {
            float d[4];
            #pragma unroll
            for (int j = 0; j < 4; j++)
                d[j] = red[aa][1 + j][0] + red[aa][1 + j][1] + red[aa][1 + j][2] + red[aa][1 + j][3]
                       + b_del[aidv[aa] * 4 + j];
            int a = av[aa];
            int m = packed[(size_t)img * A_TOTAL + a] & 31;
            const float* s = anchors + (size_t)a * 4;
            const float* t = gt + (size_t)(img * NGT + m) * 4;
            float sw = s[2] - s[0], sh = s[3] - s[1];
            float scx = s[0] + 0.5f * sw, scy = s[1] + 0.5f * sh;
            float tw = t[2] - t[0], th = t[3] - t[1];
            float tcx = t[0] + 0.5f * tw, tcy = t[1] + 0.5f * th;
            float g0 = (tcx - scx) / sw, g1 = (tcy - scy) / sh;
            float g2 = logf(tw / sw),    g3 = logf(th / sh);
            float l1 = fabsf(d[0] - g0) + fabsf(d[1] - g1) + fabsf(d[2] - g2) + fabsf(d[3] - g3);
            atomicAdd(&lsum[1], l1);
        }
    }
    __syncthreads();
    if (c == 0) {
        atomicAdd(&out[0], 0.5f * lsum[0]);
        atomicAdd(&out[1], 0.5f * lsum[1]);
    }
}

extern "C" void kernel_launch(void* const* d_in, const int* in_sizes, int n_in,
                              void* d_out, int out_size, void* d_ws, size_t ws_size,
                              hipStream_t stream) {
    const float* f_p6 = (const float*)d_in[0];
    const float* f_p5 = (const float*)d_in[1];
    const float* f_p4 = (const float*)d_in[2];
    const float* f_p3 = (const float*)d_in[3];
    const float* f_p2 = (const float*)d_in[4];
    const float* anchors = (const float*)d_in[5];
    const float* gt      = (const float*)d_in[6];
    const float* w_in  = (const float*)d_in[7];
    const float* b_in  = (const float*)d_in[8];
    const float* w_obj = (const float*)d_in[9];
    const float* b_obj = (const float*)d_in[10];
    const float* w_del = (const float*)d_in[11];
    const float* b_del = (const float*)d_in[12];

    char* ws = (char*)d_ws;
    unsigned int* best = (unsigned int*)(ws + 0);
    int* pos_total     = (int*)(ws + 160);
    int* sel_count     = (int*)(ws + 168);
    int* sel           = (int*)(ws + 192);
    unsigned char* packed = (unsigned char*)(ws + 2304);

    float* out = (float*)d_out;

    k_init<<<1, 64, 0, stream>>>(best, pos_total, sel_count, out);
    k_best<<<dim3(64, 2), 256, 0, stream>>>(anchors, gt, best);
    k_label<<<dim3((A_TOTAL + 255) / 256, 2), 256, 0, stream>>>(anchors, gt, best, packed, pos_total);
    k_scan<<<2, 1024, 0, stream>>>(packed, pos_total, sel, sel_count);
    k_eval<<<128, 256, 0, stream>>>(f_p6, f_p5, f_p4, f_p3, f_p2,
                                    anchors, gt, w_in, b_in, w_obj, b_obj,
                                    w_del, b_del, packed, sel, sel_count, out);
}

// Round 3
// 152.145 us; speedup vs baseline: 6.3112x; 1.8175x over previous
//
#include <hip/hip_runtime.h>
#include <hip/hip_bf16.h>
#include <math.h>

#define A_TOTAL 159882
#define NGT 20
#define NBLK 625   // ceil(A_TOTAL/256)

// level geometry: p6(13) p5(25) p4(50) p3(100) p2(200), 3 anchors/pos
// cumulative anchor offsets: 0, 507, 2382, 9882, 39882, 159882

__device__ __forceinline__ float iou_one(float ax1, float ay1, float ax2, float ay2,
                                         float gx1, float gy1, float gx2, float gy2) {
    float a1 = (ax2 - ax1) * (ay2 - ay1);
    float a2 = (gx2 - gx1) * (gy2 - gy1);
    float ltx = fmaxf(ax1, gx1), lty = fmaxf(ay1, gy1);
    float rbx = fminf(ax2, gx2), rby = fminf(ay2, gy2);
    float w = fmaxf(rbx - ltx, 0.f), h = fmaxf(rby - lty, 0.f);
    float inter = w * h;
    return inter / (a1 + a2 - inter);
}

__device__ __forceinline__ void decode_anchor(int a, int& W, int& aid, int& y, int& x, int& lvl) {
    int off;
    if      (a < 507)   { off = 0;     W = 13;  lvl = 0; }
    else if (a < 2382)  { off = 507;   W = 25;  lvl = 1; }
    else if (a < 9882)  { off = 2382;  W = 50;  lvl = 2; }
    else if (a < 39882) { off = 9882;  W = 100; lvl = 3; }
    else                { off = 39882; W = 200; lvl = 4; }
    int rel = a - off;
    aid = rel % 3;
    int pos = rel / 3;
    y = pos / W; x = pos % W;
}

__global__ void k_init(unsigned int* best, float* out) {
    int t = threadIdx.x;
    if (t < 2 * NGT) best[t] = 0u;
    if (t < 2) out[t] = 0.f;
}

// pass 1: best_per_gt, register-resident running max, 20 atomics per block
__global__ void k_best(const float* __restrict__ anchors, const float* __restrict__ gt,
                       unsigned int* best) {
    const int img = blockIdx.y;
    __shared__ float sgt[NGT * 4];
    __shared__ float sred[4][NGT];
    const int tid = threadIdx.x;
    if (tid < NGT * 4) sgt[tid] = gt[img * NGT * 4 + tid];
    __syncthreads();
    float vmax[NGT];
    #pragma unroll
    for (int g = 0; g < NGT; g++) vmax[g] = 0.f;
    const int stride = gridDim.x * blockDim.x;
    for (int a = blockIdx.x * blockDim.x + tid; a < A_TOTAL; a += stride) {
        float4 ab = ((const float4*)anchors)[a];
        #pragma unroll
        for (int g = 0; g < NGT; g++) {
            float v = iou_one(ab.x, ab.y, ab.z, ab.w,
                              sgt[g * 4], sgt[g * 4 + 1], sgt[g * 4 + 2], sgt[g * 4 + 3]);
            vmax[g] = fmaxf(vmax[g], v);
        }
    }
    const int lane = tid & 63, wid = tid >> 6;
    #pragma unroll
    for (int g = 0; g < NGT; g++) {
        float v = vmax[g];
        #pragma unroll
        for (int o = 32; o > 0; o >>= 1) v = fmaxf(v, __shfl_down(v, o));
        if (lane == 0) sred[wid][g] = v;
    }
    __syncthreads();
    if (tid < NGT) {
        float v = fmaxf(fmaxf(sred[0][tid], sred[1][tid]),
                        fmaxf(sred[2][tid], sred[3][tid]));
        atomicMax(&best[img * NGT + tid], __float_as_uint(v));
    }
}

// pass 2: labels + matched gt packed into a byte; per-block pos/neg counts
__global__ void k_label(const float* __restrict__ anchors, const float* __restrict__ gt,
                        const unsigned int* __restrict__ best,
                        unsigned char* packed, unsigned int* blk_cnt) {
    const int img = blockIdx.y;
    __shared__ float sgt[NGT * 4];
    __shared__ unsigned int sbest[NGT];
    __shared__ int wp[4], wn[4];
    const int tid = threadIdx.x;
    if (tid < NGT * 4) sgt[tid] = gt[img * NGT * 4 + tid];
    if (tid < NGT) sbest[tid] = best[img * NGT + tid];
    __syncthreads();
    const int a = blockIdx.x * blockDim.x + tid;
    const bool act = a < A_TOTAL;
    int code = 2;
    if (act) {
        float4 ab = ((const float4*)anchors)[a];
        float mval = -1.f; int arg = 0; bool lq = false;
        #pragma unroll
        for (int g = 0; g < NGT; g++) {
            float v = iou_one(ab.x, ab.y, ab.z, ab.w,
                              sgt[g * 4], sgt[g * 4 + 1], sgt[g * 4 + 2], sgt[g * 4 + 3]);
            if (v > mval) { mval = v; arg = g; }
            if (__float_as_uint(v) == sbest[g] && v > 0.f) lq = true;
        }
        if (lq || mval >= 0.7f) code = 1;
        else if (mval < 0.3f)   code = 0;
        packed[(size_t)img * A_TOTAL + a] = (unsigned char)((code << 5) | arg);
    }
    // per-block counts via ballot
    unsigned long long bp = __ballot(act && code == 1);
    unsigned long long bn = __ballot(act && code == 0);
    const int lane = tid & 63, wid = tid >> 6;
    if (lane == 0) { wp[wid] = __popcll(bp); wn[wid] = __popcll(bn); }
    __syncthreads();
    if (tid == 0) {
        unsigned int p = wp[0] + wp[1] + wp[2] + wp[3];
        unsigned int n = wn[0] + wn[1] + wn[2] + wn[3];
        blk_cnt[img * NBLK + blockIdx.x] = (p << 16) | n;
    }
}

// pass 3a: scan 625 block counts per image (64-bit packed to avoid overflow)
__global__ void k_offsets(const unsigned int* __restrict__ blk_cnt,
                          unsigned long long* blk_off,
                          int* pos_total, int* sel_count) {
    const int img = blockIdx.x;
    const int t = threadIdx.x;           // 1024 threads
    __shared__ unsigned long long s[1024];
    unsigned long long c = 0ULL;
    if (t < NBLK) {
        unsigned int u = blk_cnt[img * NBLK + t];
        c = ((unsigned long long)(u >> 16) << 32) | (u & 0xFFFFu);
    }
    s[t] = c;
    __syncthreads();
    #pragma unroll
    for (int off = 1; off < 1024; off <<= 1) {
        unsigned long long add = (t >= off) ? s[t - off] : 0ULL;
        __syncthreads();
        s[t] += add;
        __syncthreads();
    }
    if (t < NBLK) blk_off[img * NBLK + t] = s[t] - c;   // exclusive
    if (t == 1023) {
        unsigned long long tot = s[t];
        int tp = (int)(tot >> 32), tn = (int)(tot & 0xFFFFFFFFu);
        int npos = min(tp, 128);
        int nneg = min(tn, 256 - npos);
        pos_total[img] = tp;
        sel_count[img] = npos + nneg;
    }
}

// pass 3b: write selected anchors to deterministic slots (no atomics)
__global__ void k_select(const unsigned char* __restrict__ packed,
                         const unsigned long long* __restrict__ blk_off,
                         const int* __restrict__ pos_total,
                         int* sel) {
    const int img = blockIdx.y;
    const int t = threadIdx.x;
    const int a = blockIdx.x * 256 + t;
    const bool act = a < A_TOTAL;
    int code = 2;
    if (act) code = packed[(size_t)img * A_TOTAL + a] >> 5;
    const bool isp = act && code == 1;
    const bool isn = act && code == 0;
    unsigned long long bp = __ballot(isp);
    unsigned long long bn = __ballot(isn);
    const int lane = t & 63, wid = t >> 6;
    __shared__ int wtp[4], wtn[4];
    if (lane == 0) { wtp[wid] = __popcll(bp); wtn[wid] = __popcll(bn); }
    __syncthreads();
    const unsigned long long mlt = (1ULL << lane) - 1ULL;
    int rp = __popcll(bp & mlt);
    int rn = __popcll(bn & mlt);
    for (int w = 0; w < 4; w++) {
        if (w < wid) { rp += wtp[w]; rn += wtn[w]; }
    }
    unsigned long long bo = blk_off[img * NBLK + blockIdx.x];
    const int base_p = (int)(bo >> 32), base_n = (int)(bo & 0xFFFFFFFFu);
    const int npos = min(pos_total[img], 128);
    const int capn = 256 - npos;
    if (isp) {
        int r = base_p + rp;
        if (r < npos) sel[img * 256 + r] = a | (1 << 30);
    }
    if (isn) {
        int r = base_n + rn;
        if (r < capn) sel[img * 256 + npos + r] = a;
    }
}

// pass 4: sparse conv eval, 4 anchors per block
__global__ __launch_bounds__(256) void k_eval(
    const float* __restrict__ f0, const float* __restrict__ f1,
    const float* __restrict__ f2, const float* __restrict__ f3,
    const float* __restrict__ f4,
    const float* __restrict__ anchors, const float* __restrict__ gt,
    const float* __restrict__ w_in, const float* __restrict__ b_in,
    const float* __restrict__ w_obj, const float* __restrict__ b_obj,
    const float* __restrict__ w_del, const float* __restrict__ b_del,
    const unsigned char* __restrict__ packed,
    const int* __restrict__ sel, const int* __restrict__ sel_count,
    float* out) {
    const int img = blockIdx.x >> 6;           // 64 blocks per image
    const int slot0 = (blockIdx.x & 63) * 4;
    const int nsel = sel_count[img];
    if (slot0 >= nsel) return;

    __shared__ __align__(16) float patch[4][2304];
    __shared__ float red[4][5][4];
    __shared__ float lsum[2];
    const int c = threadIdx.x;
    if (c < 2) lsum[c] = 0.f;

    bool actv[4]; int av[4], aidv[4], isposv[4];
    #pragma unroll
    for (int aa = 0; aa < 4; aa++) {
        int slot = slot0 + aa;
        bool act = slot < nsel;
        actv[aa] = act;
        int e = act ? sel[img * 256 + slot] : 0;
        isposv[aa] = (e >> 30) & 1;
        int a = e & 0x3FFFFFFF;
        av[aa] = a;
        int W, aid, y, x, lvl;
        decode_anchor(a, W, aid, y, x, lvl);
        aidv[aa] = aid;
        const float* fm = lvl == 0 ? f0 : lvl == 1 ? f1 : lvl == 2 ? f2 : lvl == 3 ? f3 : f4;
        const float* ch = fm + ((size_t)img * 256 + c) * W * W;
        #pragma unroll
        for (int ky = 0; ky < 3; ky++)
            #pragma unroll
            for (int kx = 0; kx < 3; kx++) {
                int yy = y + ky - 1, xx = x + kx - 1;
                float v = (act && yy >= 0 && yy < W && xx >= 0 && xx < W) ? ch[yy * W + xx] : 0.f;
                patch[aa][c * 9 + ky * 3 + kx] = v;
            }
    }
    __syncthreads();

    const float bi = b_in[c];
    float acc0 = bi, acc1 = bi, acc2 = bi, acc3 = bi;
    const float4* wr = (const float4*)(w_in + (size_t)c * 2304);
    const float4* p0 = (const float4*)patch[0];
    const float4* p1 = (const float4*)patch[1];
    const float4* p2 = (const float4*)patch[2];
    const float4* p3 = (const float4*)patch[3];
    #pragma unroll 4
    for (int i = 0; i < 576; i++) {
        float4 w = wr[i];
        float4 q;
        q = p0[i]; acc0 += w.x * q.x + w.y * q.y + w.z * q.z + w.w * q.w;
        q = p1[i]; acc1 += w.x * q.x + w.y * q.y + w.z * q.z + w.w * q.w;
        q = p2[i]; acc2 += w.x * q.x + w.y * q.y + w.z * q.z + w.w * q.w;
        q = p3[i]; acc3 += w.x * q.x + w.y * q.y + w.z * q.z + w.w * q.w;
    }
    float xf[4] = { fmaxf(acc0, 0.f), fmaxf(acc1, 0.f), fmaxf(acc2, 0.f), fmaxf(acc3, 0.f) };

    float part[4][5];
    #pragma unroll
    for (int aa = 0; aa < 4; aa++) {
        part[aa][0] = xf[aa] * w_obj[aidv[aa] * 256 + c];
        #pragma unroll
        for (int j = 0; j < 4; j++)
            part[aa][1 + j] = xf[aa] * w_del[(aidv[aa] * 4 + j) * 256 + c];
    }
    const int lane = c & 63, wid = c >> 6;
    #pragma unroll
    for (int o = 32; o > 0; o >>= 1)
        #pragma unroll
        for (int aa = 0; aa < 4; aa++)
            #pragma unroll
            for (int j = 0; j < 5; j++)
                part[aa][j] += __shfl_down(part[aa][j], o);
    if (lane == 0)
        #pragma unroll
        for (int aa = 0; aa < 4; aa++)
            #pragma unroll
            for (int j = 0; j < 5; j++)
                red[aa][j][wid] = part[aa][j];
    __syncthreads();

    if (c < 4 && actv[c]) {
        const int aa = c;
        float logit = red[aa][0][0] + red[aa][0][1] + red[aa][0][2] + red[aa][0][3] + b_obj[aidv[aa]];
        float tgt = isposv[aa] ? 1.f : 0.f;
        float bce = fmaxf(logit, 0.f) - logit * tgt + log1pf(expf(-fabsf(logit)));
        atomicAdd(&lsum[0], bce);
        if (isposv[aa]) {
            float d[4];
            #pragma unroll
            for (int j = 0; j < 4; j++)
                d[j] = red[aa][1 + j][0] + red[aa][1 + j][1] + red[aa][1 + j][2] + red[aa][1 + j][3]
                       + b_del[aidv[aa] * 4 + j];
            int a = av[aa];
            int m = packed[(size_t)img * A_TOTAL + a] & 31;
            const float* s = anchors + (size_t)a * 4;
            const float* t = gt + (size_t)(img * NGT + m) * 4;
            float sw = s[2] - s[0], sh = s[3] - s[1];
            float scx = s[0] + 0.5f * sw, scy = s[1] + 0.5f * sh;
            float tw = t[2] - t[0], th = t[3] - t[1];
            float tcx = t[0] + 0.5f * tw, tcy = t[1] + 0.5f * th;
            float g0 = (tcx - scx) / sw, g1 = (tcy - scy) / sh;
            float g2 = logf(tw / sw),    g3 = logf(th / sh);
            float l1 = fabsf(d[0] - g0) + fabsf(d[1] - g1) + fabsf(d[2] - g2) + fabsf(d[3] - g3);
            atomicAdd(&lsum[1], l1);
        }
    }
    __syncthreads();
    if (c == 0) {
        atomicAdd(&out[0], 0.5f * lsum[0]);
        atomicAdd(&out[1], 0.5f * lsum[1]);
    }
}

extern "C" void kernel_launch(void* const* d_in, const int* in_sizes, int n_in,
                              void* d_out, int out_size, void* d_ws, size_t ws_size,
                              hipStream_t stream) {
    const float* f_p6 = (const float*)d_in[0];
    const float* f_p5 = (const float*)d_in[1];
    const float* f_p4 = (const float*)d_in[2];
    const float* f_p3 = (const float*)d_in[3];
    const float* f_p2 = (const float*)d_in[4];
    const float* anchors = (const float*)d_in[5];
    const float* gt      = (const float*)d_in[6];
    const float* w_in  = (const float*)d_in[7];
    const float* b_in  = (const float*)d_in[8];
    const float* w_obj = (const float*)d_in[9];
    const float* b_obj = (const float*)d_in[10];
    const float* w_del = (const float*)d_in[11];
    const float* b_del = (const float*)d_in[12];

    // workspace layout
    char* ws = (char*)d_ws;
    unsigned int* best        = (unsigned int*)(ws + 0);        // 160 B
    int* pos_total            = (int*)(ws + 160);               // 8 B
    int* sel_count            = (int*)(ws + 168);               // 8 B
    int* sel                  = (int*)(ws + 192);               // 2048 B
    unsigned int* blk_cnt     = (unsigned int*)(ws + 2240);     // 2*625*4 = 5000 B
    unsigned long long* blk_off = (unsigned long long*)(ws + 7296); // 2*625*8 = 10000 B
    unsigned char* packed     = (unsigned char*)(ws + 17344);   // 2*A_TOTAL B

    float* out = (float*)d_out;

    k_init<<<1, 64, 0, stream>>>(best, out);
    k_best<<<dim3(64, 2), 256, 0, stream>>>(anchors, gt, best);
    k_label<<<dim3(NBLK, 2), 256, 0, stream>>>(anchors, gt, best, packed, blk_cnt);
    k_offsets<<<2, 1024, 0, stream>>>(blk_cnt, blk_off, pos_total, sel_count);
    k_select<<<dim3(NBLK, 2), 256, 0, stream>>>(packed, blk_off, pos_total, sel);
    k_eval<<<128, 256, 0, stream>>>(f_p6, f_p5, f_p4, f_p3, f_p2,
                                    anchors, gt, w_in, b_in, w_obj, b_obj,
                                    w_del, b_del, packed, sel, sel_count, out);
}

// Round 4
// 122.933 us; speedup vs baseline: 7.8109x; 1.2376x over previous
//
#include <hip/hip_runtime.h>
#include <hip/hip_bf16.h>
#include <math.h>

#define A_TOTAL 159882
#define NGT 20
#define NBLK 625   // ceil(A_TOTAL/256)
#define CHUNKS 4
#define CI_PER 64          // input channels per chunk
#define TERMS (CI_PER * 9) // 576 floats per (channel-row, chunk)
#define ANB 4              // anchors per conv block

// level geometry: p6(13) p5(25) p4(50) p3(100) p2(200), 3 anchors/pos
// cumulative anchor offsets: 0, 507, 2382, 9882, 39882, 159882

__device__ __forceinline__ float iou_one(float ax1, float ay1, float ax2, float ay2,
                                         float gx1, float gy1, float gx2, float gy2) {
    float a1 = (ax2 - ax1) * (ay2 - ay1);
    float a2 = (gx2 - gx1) * (gy2 - gy1);
    float ltx = fmaxf(ax1, gx1), lty = fmaxf(ay1, gy1);
    float rbx = fminf(ax2, gx2), rby = fminf(ay2, gy2);
    float w = fmaxf(rbx - ltx, 0.f), h = fmaxf(rby - lty, 0.f);
    float inter = w * h;
    return inter / (a1 + a2 - inter);
}

__device__ __forceinline__ void decode_anchor(int a, int& W, int& aid, int& y, int& x, int& lvl) {
    int off;
    if      (a < 507)   { off = 0;     W = 13;  lvl = 0; }
    else if (a < 2382)  { off = 507;   W = 25;  lvl = 1; }
    else if (a < 9882)  { off = 2382;  W = 50;  lvl = 2; }
    else if (a < 39882) { off = 9882;  W = 100; lvl = 3; }
    else                { off = 39882; W = 200; lvl = 4; }
    int rel = a - off;
    aid = rel % 3;
    int pos = rel / 3;
    y = pos / W; x = pos % W;
}

__global__ void k_init(unsigned int* best, float* out) {
    int t = threadIdx.x;
    if (t < 2 * NGT) best[t] = 0u;
    if (t < 2) out[t] = 0.f;
}

// pass 1: best_per_gt, register-resident running max, 20 atomics per block
__global__ void k_best(const float* __restrict__ anchors, const float* __restrict__ gt,
                       unsigned int* best) {
    const int img = blockIdx.y;
    __shared__ float sgt[NGT * 4];
    __shared__ float sred[4][NGT];
    const int tid = threadIdx.x;
    if (tid < NGT * 4) sgt[tid] = gt[img * NGT * 4 + tid];
    __syncthreads();
    float vmax[NGT];
    #pragma unroll
    for (int g = 0; g < NGT; g++) vmax[g] = 0.f;
    const int stride = gridDim.x * blockDim.x;
    for (int a = blockIdx.x * blockDim.x + tid; a < A_TOTAL; a += stride) {
        float4 ab = ((const float4*)anchors)[a];
        #pragma unroll
        for (int g = 0; g < NGT; g++) {
            float v = iou_one(ab.x, ab.y, ab.z, ab.w,
                              sgt[g * 4], sgt[g * 4 + 1], sgt[g * 4 + 2], sgt[g * 4 + 3]);
            vmax[g] = fmaxf(vmax[g], v);
        }
    }
    const int lane = tid & 63, wid = tid >> 6;
    #pragma unroll
    for (int g = 0; g < NGT; g++) {
        float v = vmax[g];
        #pragma unroll
        for (int o = 32; o > 0; o >>= 1) v = fmaxf(v, __shfl_down(v, o));
        if (lane == 0) sred[wid][g] = v;
    }
    __syncthreads();
    if (tid < NGT) {
        float v = fmaxf(fmaxf(sred[0][tid], sred[1][tid]),
                        fmaxf(sred[2][tid], sred[3][tid]));
        atomicMax(&best[img * NGT + tid], __float_as_uint(v));
    }
}

// pass 2: labels + matched gt packed into a byte; per-block pos/neg counts
__global__ void k_label(const float* __restrict__ anchors, const float* __restrict__ gt,
                        const unsigned int* __restrict__ best,
                        unsigned char* packed, unsigned int* blk_cnt) {
    const int img = blockIdx.y;
    __shared__ float sgt[NGT * 4];
    __shared__ unsigned int sbest[NGT];
    __shared__ int wp[4], wn[4];
    const int tid = threadIdx.x;
    if (tid < NGT * 4) sgt[tid] = gt[img * NGT * 4 + tid];
    if (tid < NGT) sbest[tid] = best[img * NGT + tid];
    __syncthreads();
    const int a = blockIdx.x * blockDim.x + tid;
    const bool act = a < A_TOTAL;
    int code = 2;
    if (act) {
        float4 ab = ((const float4*)anchors)[a];
        float mval = -1.f; int arg = 0; bool lq = false;
        #pragma unroll
        for (int g = 0; g < NGT; g++) {
            float v = iou_one(ab.x, ab.y, ab.z, ab.w,
                              sgt[g * 4], sgt[g * 4 + 1], sgt[g * 4 + 2], sgt[g * 4 + 3]);
            if (v > mval) { mval = v; arg = g; }
            if (__float_as_uint(v) == sbest[g] && v > 0.f) lq = true;
        }
        if (lq || mval >= 0.7f) code = 1;
        else if (mval < 0.3f)   code = 0;
        packed[(size_t)img * A_TOTAL + a] = (unsigned char)((code << 5) | arg);
    }
    unsigned long long bp = __ballot(act && code == 1);
    unsigned long long bn = __ballot(act && code == 0);
    const int lane = tid & 63, wid = tid >> 6;
    if (lane == 0) { wp[wid] = __popcll(bp); wn[wid] = __popcll(bn); }
    __syncthreads();
    if (tid == 0) {
        unsigned int p = wp[0] + wp[1] + wp[2] + wp[3];
        unsigned int n = wn[0] + wn[1] + wn[2] + wn[3];
        blk_cnt[img * NBLK + blockIdx.x] = (p << 16) | n;
    }
}

// pass 3a: scan 625 block counts per image (64-bit packed)
__global__ void k_offsets(const unsigned int* __restrict__ blk_cnt,
                          unsigned long long* blk_off,
                          int* pos_total, int* sel_count) {
    const int img = blockIdx.x;
    const int t = threadIdx.x;           // 1024 threads
    __shared__ unsigned long long s[1024];
    unsigned long long c = 0ULL;
    if (t < NBLK) {
        unsigned int u = blk_cnt[img * NBLK + t];
        c = ((unsigned long long)(u >> 16) << 32) | (u & 0xFFFFu);
    }
    s[t] = c;
    __syncthreads();
    #pragma unroll
    for (int off = 1; off < 1024; off <<= 1) {
        unsigned long long add = (t >= off) ? s[t - off] : 0ULL;
        __syncthreads();
        s[t] += add;
        __syncthreads();
    }
    if (t < NBLK) blk_off[img * NBLK + t] = s[t] - c;   // exclusive
    if (t == 1023) {
        unsigned long long tot = s[t];
        int tp = (int)(tot >> 32), tn = (int)(tot & 0xFFFFFFFFu);
        int npos = min(tp, 128);
        int nneg = min(tn, 256 - npos);
        pos_total[img] = tp;
        sel_count[img] = npos + nneg;
    }
}

// pass 3b: write selected anchors to deterministic slots (no atomics)
__global__ void k_select(const unsigned char* __restrict__ packed,
                         const unsigned long long* __restrict__ blk_off,
                         const int* __restrict__ pos_total,
                         int* sel) {
    const int img = blockIdx.y;
    const int t = threadIdx.x;
    const int a = blockIdx.x * 256 + t;
    const bool act = a < A_TOTAL;
    int code = 2;
    if (act) code = packed[(size_t)img * A_TOTAL + a] >> 5;
    const bool isp = act && code == 1;
    const bool isn = act && code == 0;
    unsigned long long bp = __ballot(isp);
    unsigned long long bn = __ballot(isn);
    const int lane = t & 63, wid = t >> 6;
    __shared__ int wtp[4], wtn[4];
    if (lane == 0) { wtp[wid] = __popcll(bp); wtn[wid] = __popcll(bn); }
    __syncthreads();
    const unsigned long long mlt = (1ULL << lane) - 1ULL;
    int rp = __popcll(bp & mlt);
    int rn = __popcll(bn & mlt);
    for (int w = 0; w < 4; w++) {
        if (w < wid) { rp += wtp[w]; rn += wtn[w]; }
    }
    unsigned long long bo = blk_off[img * NBLK + blockIdx.x];
    const int base_p = (int)(bo >> 32), base_n = (int)(bo & 0xFFFFFFFFu);
    const int npos = min(pos_total[img], 128);
    const int capn = 256 - npos;
    if (isp) {
        int r = base_p + rp;
        if (r < npos) sel[img * 256 + r] = a | (1 << 30);
    }
    if (isn) {
        int r = base_n + rn;
        if (r < capn) sel[img * 256 + npos + r] = a;
    }
}

// pass 4a: partial conv — 4 anchors x 64-input-channel chunk per block
__global__ __launch_bounds__(256) void k_conv(
    const float* __restrict__ f0, const float* __restrict__ f1,
    const float* __restrict__ f2, const float* __restrict__ f3,
    const float* __restrict__ f4,
    const float* __restrict__ w_in,
    const int* __restrict__ sel, const int* __restrict__ sel_count,
    float* __restrict__ xpart) {
    const int img = blockIdx.z;
    const int chunk = blockIdx.y;
    const int slot0 = blockIdx.x * ANB;
    const int nsel = sel_count[img];
    if (slot0 >= nsel) return;

    __shared__ __align__(16) float patch[ANB][TERMS];   // 9216 B
    __shared__ int s_W[ANB], s_y[ANB], s_x[ANB], s_act[ANB];
    __shared__ const float* s_fm[ANB];
    const int tid = threadIdx.x;

    if (tid < ANB) {
        int slot = slot0 + tid;
        bool act = slot < nsel;
        int e = act ? sel[img * 256 + slot] : 0;
        int a = e & 0x3FFFFFFF;
        int W, aid, y, x, lvl;
        decode_anchor(a, W, aid, y, x, lvl);
        s_W[tid] = W; s_y[tid] = y; s_x[tid] = x; s_act[tid] = act ? 1 : 0;
        s_fm[tid] = (lvl == 0 ? f0 : lvl == 1 ? f1 : lvl == 2 ? f2 : lvl == 3 ? f3 : f4);
    }
    __syncthreads();

    // stage ANB*TERMS = 2304 patch values
    for (int p = tid; p < ANB * TERMS; p += 256) {
        int aa = p / TERMS;
        int idx = p - aa * TERMS;
        int cil = idx / 9;
        int r = idx - cil * 9;
        int ky = r / 3, kx = r - ky * 3;
        int W = s_W[aa];
        int yy = s_y[aa] + ky - 1, xx = s_x[aa] + kx - 1;
        float v = 0.f;
        if (s_act[aa] && yy >= 0 && yy < W && xx >= 0 && xx < W) {
            const float* fm = s_fm[aa];
            int ci = chunk * CI_PER + cil;
            v = fm[(((size_t)img * 256 + ci) * W + yy) * W + xx];
        }
        patch[aa][idx] = v;
    }
    __syncthreads();

    const int c = tid;
    const float4* wr = (const float4*)(w_in + (size_t)c * 2304 + chunk * TERMS);
    const float4* p0 = (const float4*)patch[0];
    const float4* p1 = (const float4*)patch[1];
    const float4* p2 = (const float4*)patch[2];
    const float4* p3 = (const float4*)patch[3];
    float acc0 = 0.f, acc1 = 0.f, acc2 = 0.f, acc3 = 0.f;
    #pragma unroll 4
    for (int i = 0; i < TERMS / 4; i++) {
        float4 w = wr[i];
        float4 q;
        q = p0[i]; acc0 += w.x * q.x + w.y * q.y + w.z * q.z + w.w * q.w;
        q = p1[i]; acc1 += w.x * q.x + w.y * q.y + w.z * q.z + w.w * q.w;
        q = p2[i]; acc2 += w.x * q.x + w.y * q.y + w.z * q.z + w.w * q.w;
        q = p3[i]; acc3 += w.x * q.x + w.y * q.y + w.z * q.z + w.w * q.w;
    }
    float acc[ANB] = {acc0, acc1, acc2, acc3};
    #pragma unroll
    for (int aa = 0; aa < ANB; aa++) {
        int slot = slot0 + aa;
        if (slot < nsel)
            xpart[(((size_t)img * CHUNKS + chunk) * 256 + slot) * 256 + c] = acc[aa];
    }
}

// pass 4b: reduce chunks + bias + relu, 5 block-dots, per-anchor losses
__global__ __launch_bounds__(256) void k_post(
    const float* __restrict__ xpart,
    const float* __restrict__ anchors, const float* __restrict__ gt,
    const float* __restrict__ b_in,
    const float* __restrict__ w_obj, const float* __restrict__ b_obj,
    const float* __restrict__ w_del, const float* __restrict__ b_del,
    const unsigned char* __restrict__ packed,
    const int* __restrict__ sel, const int* __restrict__ sel_count,
    float* __restrict__ lossbuf) {
    const int img = blockIdx.y;
    const int slot = blockIdx.x;
    const int nsel = sel_count[img];
    if (slot >= nsel) return;
    const int e = sel[img * 256 + slot];
    const int is_pos = (e >> 30) & 1;
    const int a = e & 0x3FFFFFFF;
    int W, aid, y, x, lvl;
    decode_anchor(a, W, aid, y, x, lvl);

    const int c = threadIdx.x;
    float s = b_in[c];
    #pragma unroll
    for (int ch = 0; ch < CHUNKS; ch++)
        s += xpart[(((size_t)img * CHUNKS + ch) * 256 + slot) * 256 + c];
    float xf = fmaxf(s, 0.f);

    float part[5];
    part[0] = xf * w_obj[aid * 256 + c];
    #pragma unroll
    for (int j = 0; j < 4; j++) part[1 + j] = xf * w_del[(aid * 4 + j) * 256 + c];
    const int lane = c & 63, wid = c >> 6;
    __shared__ float red[5][4];
    #pragma unroll
    for (int o = 32; o > 0; o >>= 1)
        #pragma unroll
        for (int j = 0; j < 5; j++) part[j] += __shfl_down(part[j], o);
    if (lane == 0)
        #pragma unroll
        for (int j = 0; j < 5; j++) red[j][wid] = part[j];
    __syncthreads();

    if (c == 0) {
        float logit = red[0][0] + red[0][1] + red[0][2] + red[0][3] + b_obj[aid];
        float tgt = is_pos ? 1.f : 0.f;
        float bce = fmaxf(logit, 0.f) - logit * tgt + log1pf(expf(-fabsf(logit)));
        float l1 = 0.f;
        if (is_pos) {
            float d[4];
            #pragma unroll
            for (int j = 0; j < 4; j++)
                d[j] = red[1 + j][0] + red[1 + j][1] + red[1 + j][2] + red[1 + j][3] + b_del[aid * 4 + j];
            int m = packed[(size_t)img * A_TOTAL + a] & 31;
            const float* sp = anchors + (size_t)a * 4;
            const float* t = gt + (size_t)(img * NGT + m) * 4;
            float sw = sp[2] - sp[0], sh = sp[3] - sp[1];
            float scx = sp[0] + 0.5f * sw, scy = sp[1] + 0.5f * sh;
            float tw = t[2] - t[0], th = t[3] - t[1];
            float tcx = t[0] + 0.5f * tw, tcy = t[1] + 0.5f * th;
            float g0 = (tcx - scx) / sw, g1 = (tcy - scy) / sh;
            float g2 = logf(tw / sw),    g3 = logf(th / sh);
            l1 = fabsf(d[0] - g0) + fabsf(d[1] - g1) + fabsf(d[2] - g2) + fabsf(d[3] - g3);
        }
        lossbuf[(img * 256 + slot) * 2 + 0] = bce;
        lossbuf[(img * 256 + slot) * 2 + 1] = l1;
    }
}

// pass 5: deterministic tree-sum of per-anchor losses -> out[2]
__global__ void k_final(const float* __restrict__ lossbuf,
                        const int* __restrict__ sel_count,
                        float* __restrict__ out) {
    const int t = threadIdx.x;      // 512 threads
    const int img = t >> 8, slot = t & 255;
    float bce = 0.f, l1 = 0.f;
    if (slot < sel_count[img]) {
        bce = lossbuf[t * 2 + 0];
        l1  = lossbuf[t * 2 + 1];
    }
    const int lane = t & 63, wid = t >> 6;
    #pragma unroll
    for (int o = 32; o > 0; o >>= 1) {
        bce += __shfl_down(bce, o);
        l1  += __shfl_down(l1, o);
    }
    __shared__ float rb[8], rl[8];
    if (lane == 0) { rb[wid] = bce; rl[wid] = l1; }
    __syncthreads();
    if (t == 0) {
        float sb = 0.f, sl = 0.f;
        #pragma unroll
        for (int w = 0; w < 8; w++) { sb += rb[w]; sl += rl[w]; }
        out[0] = 0.5f * sb;
        out[1] = 0.5f * sl;
    }
}

// fallback monolithic eval (round-3 proven) if workspace is too small
__global__ __launch_bounds__(256) void k_eval(
    const float* __restrict__ f0, const float* __restrict__ f1,
    const float* __restrict__ f2, const float* __restrict__ f3,
    const float* __restrict__ f4,
    const float* __restrict__ anchors, const float* __restrict__ gt,
    const float* __restrict__ w_in, const float* __restrict__ b_in,
    const float* __restrict__ w_obj, const float* __restrict__ b_obj,
    const float* __restrict__ w_del, const float* __restrict__ b_del,
    const unsigned char* __restrict__ packed,
    const int* __restrict__ sel, const int* __restrict__ sel_count,
    float* out) {
    const int img = blockIdx.x >> 6;
    const int slot0 = (blockIdx.x & 63) * 4;
    const int nsel = sel_count[img];
    if (slot0 >= nsel) return;

    __shared__ __align__(16) float patch[4][2304];
    __shared__ float red[4][5][4];
    __shared__ float lsum[2];
    const int c = threadIdx.x;
    if (c < 2) lsum[c] = 0.f;

    bool actv[4]; int av[4], aidv[4], isposv[4];
    #pragma unroll
    for (int aa = 0; aa < 4; aa++) {
        int slot = slot0 + aa;
        bool act = slot < nsel;
        actv[aa] = act;
        int e = act ? sel[img * 256 + slot] : 0;
        isposv[aa] = (e >> 30) & 1;
        int a = e & 0x3FFFFFFF;
        av[aa] = a;
        int W, aid, y, x, lvl;
        decode_anchor(a, W, aid, y, x, lvl);
        aidv[aa] = aid;
        const float* fm = lvl == 0 ? f0 : lvl == 1 ? f1 : lvl == 2 ? f2 : lvl == 3 ? f3 : f4;
        const float* ch = fm + ((size_t)img * 256 + c) * W * W;
        #pragma unroll
        for (int ky = 0; ky < 3; ky++)
            #pragma unroll
            for (int kx = 0; kx < 3; kx++) {
                int yy = y + ky - 1, xx = x + kx - 1;
                float v = (act && yy >= 0 && yy < W && xx >= 0 && xx < W) ? ch[yy * W + xx] : 0.f;
                patch[aa][c * 9 + ky * 3 + kx] = v;
            }
    }
    __syncthreads();

    const float bi = b_in[c];
    float acc0 = bi, acc1 = bi, acc2 = bi, acc3 = bi;
    const float4* wr = (const float4*)(w_in + (size_t)c * 2304);
    const float4* p0 = (const float4*)patch[0];
    const float4* p1 = (const float4*)patch[1];
    const float4* p2 = (const float4*)patch[2];
    const float4* p3 = (const float4*)patch[3];
    #pragma unroll 4
    for (int i = 0; i < 576; i++) {
        float4 w = wr[i];
        float4 q;
        q = p0[i]; acc0 += w.x * q.x + w.y * q.y + w.z * q.z + w.w * q.w;
        q = p1[i]; acc1 += w.x * q.x + w.y * q.y + w.z * q.z + w.w * q.w;
        q = p2[i]; acc2 += w.x * q.x + w.y * q.y + w.z * q.z + w.w * q.w;
        q = p3[i]; acc3 += w.x * q.x + w.y * q.y + w.z * q.z + w.w * q.w;
    }
    float xf[4] = { fmaxf(acc0, 0.f), fmaxf(acc1, 0.f), fmaxf(acc2, 0.f), fmaxf(acc3, 0.f) };

    float part[4][5];
    #pragma unroll
    for (int aa = 0; aa < 4; aa++) {
        part[aa][0] = xf[aa] * w_obj[aidv[aa] * 256 + c];
        #pragma unroll
        for (int j = 0; j < 4; j++)
            part[aa][1 + j] = xf[aa] * w_del[(aidv[aa] * 4 + j) * 256 + c];
    }
    const int lane = c & 63, wid = c >> 6;
    #pragma unroll
    for (int o = 32; o > 0; o >>= 1)
        #pragma unroll
        for (int aa = 0; aa < 4; aa++)
            #pragma unroll
            for (int j = 0; j < 5; j++)
                part[aa][j] += __shfl_down(part[aa][j], o);
    if (lane == 0)
        #pragma unroll
        for (int aa = 0; aa < 4; aa++)
            #pragma unroll
            for (int j = 0; j < 5; j++)
                red[aa][j][wid] = part[aa][j];
    __syncthreads();

    if (c < 4 && actv[c]) {
        const int aa = c;
        float logit = red[aa][0][0] + red[aa][0][1] + red[aa][0][2] + red[aa][0][3] + b_obj[aidv[aa]];
        float tgt = isposv[aa] ? 1.f : 0.f;
        float bce = fmaxf(logit, 0.f) - logit * tgt + log1pf(expf(-fabsf(logit)));
        atomicAdd(&lsum[0], bce);
        if (isposv[aa]) {
            float d[4];
            #pragma unroll
            for (int j = 0; j < 4; j++)
                d[j] = red[aa][1 + j][0] + red[aa][1 + j][1] + red[aa][1 + j][2] + red[aa][1 + j][3]
                       + b_del[aidv[aa] * 4 + j];
            int a = av[aa];
            int m = packed[(size_t)img * A_TOTAL + a] & 31;
            const float* s = anchors + (size_t)a * 4;
            const float* t = gt + (size_t)(img * NGT + m) * 4;
            float sw = s[2] - s[0], sh = s[3] - s[1];
            float scx = s[0] + 0.5f * sw, scy = s[1] + 0.5f * sh;
            float tw = t[2] - t[0], th = t[3] - t[1];
            float tcx = t[0] + 0.5f * tw, tcy = t[1] + 0.5f * th;
            float g0 = (tcx - scx) / sw, g1 = (tcy - scy) / sh;
            float g2 = logf(tw / sw),    g3 = logf(th / sh);
            float l1 = fabsf(d[0] - g0) + fabsf(d[1] - g1) + fabsf(d[2] - g2) + fabsf(d[3] - g3);
            atomicAdd(&lsum[1], l1);
        }
    }
    __syncthreads();
    if (c == 0) {
        atomicAdd(&out[0], 0.5f * lsum[0]);
        atomicAdd(&out[1], 0.5f * lsum[1]);
    }
}

extern "C" void kernel_launch(void* const* d_in, const int* in_sizes, int n_in,
                              void* d_out, int out_size, void* d_ws, size_t ws_size,
                              hipStream_t stream) {
    const float* f_p6 = (const float*)d_in[0];
    const float* f_p5 = (const float*)d_in[1];
    const float* f_p4 = (const float*)d_in[2];
    const float* f_p3 = (const float*)d_in[3];
    const float* f_p2 = (const float*)d_in[4];
    const float* anchors = (const float*)d_in[5];
    const float* gt      = (const float*)d_in[6];
    const float* w_in  = (const float*)d_in[7];
    const float* b_in  = (const float*)d_in[8];
    const float* w_obj = (const float*)d_in[9];
    const float* b_obj = (const float*)d_in[10];
    const float* w_del = (const float*)d_in[11];
    const float* b_del = (const float*)d_in[12];

    // workspace layout
    char* ws = (char*)d_ws;
    unsigned int* best          = (unsigned int*)(ws + 0);        // 160 B
    int* pos_total              = (int*)(ws + 160);               // 8 B
    int* sel_count              = (int*)(ws + 168);               // 8 B
    int* sel                    = (int*)(ws + 192);               // 2048 B
    unsigned int* blk_cnt       = (unsigned int*)(ws + 2240);     // 5000 B
    unsigned long long* blk_off = (unsigned long long*)(ws + 7296); // 10000 B
    unsigned char* packed       = (unsigned char*)(ws + 17344);   // 319764 B -> 337108
    float* lossbuf              = (float*)(ws + 337152);          // 4096 B  -> 341248
    float* xpart                = (float*)(ws + 341248);          // 2*4*256*256*4 = 2097152 -> 2438400
    const size_t WS_NEEDED = 2438400;

    float* out = (float*)d_out;

    k_init<<<1, 64, 0, stream>>>(best, out);
    k_best<<<dim3(64, 2), 256, 0, stream>>>(anchors, gt, best);
    k_label<<<dim3(NBLK, 2), 256, 0, stream>>>(anchors, gt, best, packed, blk_cnt);
    k_offsets<<<2, 1024, 0, stream>>>(blk_cnt, blk_off, pos_total, sel_count);
    k_select<<<dim3(NBLK, 2), 256, 0, stream>>>(packed, blk_off, pos_total, sel);

    if (ws_size >= WS_NEEDED) {
        k_conv<<<dim3(64, CHUNKS, 2), 256, 0, stream>>>(f_p6, f_p5, f_p4, f_p3, f_p2,
                                                        w_in, sel, sel_count, xpart);
        k_post<<<dim3(256, 2), 256, 0, stream>>>(xpart, anchors, gt, b_in,
                                                 w_obj, b_obj, w_del, b_del,
                                                 packed, sel, sel_count, lossbuf);
        k_final<<<1, 512, 0, stream>>>(lossbuf, sel_count, out);
    } else {
        k_eval<<<128, 256, 0, stream>>>(f_p6, f_p5, f_p4, f_p3, f_p2,
                                        anchors, gt, w_in, b_in, w_obj, b_obj,
                                        w_del, b_del, packed, sel, sel_count, out);
    }
}

// Round 5
// 88.039 us; speedup vs baseline: 10.9067x; 1.3964x over previous
//
#include <hip/hip_runtime.h>
#include <hip/hip_bf16.h>
#include <math.h>

#define A_TOTAL 159882
#define NGT 20
#define NBLK 625   // ceil(A_TOTAL/256)
#define CHUNKS 4
#define CI_PER 64          // input channels per chunk
#define TERMS (CI_PER * 9) // 576 floats per (channel-row, chunk)
#define ANB 4              // anchors per conv block

// level geometry: p6(13) p5(25) p4(50) p3(100) p2(200), 3 anchors/pos
// cumulative anchor offsets: 0, 507, 2382, 9882, 39882, 159882

__device__ __forceinline__ float iou_one(float ax1, float ay1, float ax2, float ay2,
                                         float gx1, float gy1, float gx2, float gy2) {
    float a1 = (ax2 - ax1) * (ay2 - ay1);
    float a2 = (gx2 - gx1) * (gy2 - gy1);
    float ltx = fmaxf(ax1, gx1), lty = fmaxf(ay1, gy1);
    float rbx = fminf(ax2, gx2), rby = fminf(ay2, gy2);
    float w = fmaxf(rbx - ltx, 0.f), h = fmaxf(rby - lty, 0.f);
    float inter = w * h;
    return inter / (a1 + a2 - inter);
}

__device__ __forceinline__ void decode_anchor(int a, int& W, int& aid, int& y, int& x, int& lvl) {
    int off;
    if      (a < 507)   { off = 0;     W = 13;  lvl = 0; }
    else if (a < 2382)  { off = 507;   W = 25;  lvl = 1; }
    else if (a < 9882)  { off = 2382;  W = 50;  lvl = 2; }
    else if (a < 39882) { off = 9882;  W = 100; lvl = 3; }
    else                { off = 39882; W = 200; lvl = 4; }
    int rel = a - off;
    aid = rel % 3;
    int pos = rel / 3;
    y = pos / W; x = pos % W;
}

__global__ void k_init(unsigned int* best, float* out) {
    int t = threadIdx.x;
    if (t < 2 * NGT) best[t] = 0u;
    if (t < 2) out[t] = 0.f;
}

// pass 1a: per-block column maxes of the IoU matrix (full grid, no atomics)
__global__ __launch_bounds__(256) void k_bmax(const float* __restrict__ anchors,
                                              const float* __restrict__ gt,
                                              float* __restrict__ pmax) {
    const int img = blockIdx.y;
    __shared__ float sgt[NGT * 4];
    __shared__ float sred[4][NGT];
    const int tid = threadIdx.x;
    if (tid < NGT * 4) sgt[tid] = gt[img * NGT * 4 + tid];
    __syncthreads();
    const int a = blockIdx.x * 256 + tid;
    float4 ab = make_float4(0.f, 0.f, 1.f, 1.f);
    if (a < A_TOTAL) ab = ((const float4*)anchors)[a];
    float v[NGT];
    #pragma unroll
    for (int g = 0; g < NGT; g++) {
        float u = (a < A_TOTAL)
                    ? iou_one(ab.x, ab.y, ab.z, ab.w,
                              sgt[g * 4], sgt[g * 4 + 1], sgt[g * 4 + 2], sgt[g * 4 + 3])
                    : 0.f;
        v[g] = u;
    }
    const int lane = tid & 63, wid = tid >> 6;
    #pragma unroll
    for (int g = 0; g < NGT; g++) {
        float u = v[g];
        #pragma unroll
        for (int o = 32; o > 0; o >>= 1) u = fmaxf(u, __shfl_down(u, o));
        if (lane == 0) sred[wid][g] = u;
    }
    __syncthreads();
    if (tid < NGT) {
        float u = fmaxf(fmaxf(sred[0][tid], sred[1][tid]),
                        fmaxf(sred[2][tid], sred[3][tid]));
        pmax[((size_t)img * NBLK + blockIdx.x) * NGT + tid] = u;
    }
}

// pass 1b: tree-reduce 625 partials per (img, gt) -> best (single store, no atomics)
__global__ void k_bred(const float* __restrict__ pmax, unsigned int* __restrict__ best) {
    const int g = blockIdx.x, img = blockIdx.y;
    const int tid = threadIdx.x;   // 256
    float v = 0.f;
    for (int i = tid; i < NBLK; i += 256)
        v = fmaxf(v, pmax[((size_t)img * NBLK + i) * NGT + g]);
    const int lane = tid & 63, wid = tid >> 6;
    #pragma unroll
    for (int o = 32; o > 0; o >>= 1) v = fmaxf(v, __shfl_down(v, o));
    __shared__ float r[4];
    if (lane == 0) r[wid] = v;
    __syncthreads();
    if (tid == 0)
        best[img * NGT + g] = __float_as_uint(fmaxf(fmaxf(r[0], r[1]), fmaxf(r[2], r[3])));
}

// fallback pass 1 (round-2 proven): register running max + 20 atomics/block
__global__ void k_best(const float* __restrict__ anchors, const float* __restrict__ gt,
                       unsigned int* best) {
    const int img = blockIdx.y;
    __shared__ float sgt[NGT * 4];
    __shared__ float sred[4][NGT];
    const int tid = threadIdx.x;
    if (tid < NGT * 4) sgt[tid] = gt[img * NGT * 4 + tid];
    __syncthreads();
    float vmax[NGT];
    #pragma unroll
    for (int g = 0; g < NGT; g++) vmax[g] = 0.f;
    const int stride = gridDim.x * blockDim.x;
    for (int a = blockIdx.x * blockDim.x + tid; a < A_TOTAL; a += stride) {
        float4 ab = ((const float4*)anchors)[a];
        #pragma unroll
        for (int g = 0; g < NGT; g++) {
            float v = iou_one(ab.x, ab.y, ab.z, ab.w,
                              sgt[g * 4], sgt[g * 4 + 1], sgt[g * 4 + 2], sgt[g * 4 + 3]);
            vmax[g] = fmaxf(vmax[g], v);
        }
    }
    const int lane = tid & 63, wid = tid >> 6;
    #pragma unroll
    for (int g = 0; g < NGT; g++) {
        float v = vmax[g];
        #pragma unroll
        for (int o = 32; o > 0; o >>= 1) v = fmaxf(v, __shfl_down(v, o));
        if (lane == 0) sred[wid][g] = v;
    }
    __syncthreads();
    if (tid < NGT) {
        float v = fmaxf(fmaxf(sred[0][tid], sred[1][tid]),
                        fmaxf(sred[2][tid], sred[3][tid]));
        atomicMax(&best[img * NGT + tid], __float_as_uint(v));
    }
}

// pass 2: labels + matched gt packed into a byte; per-block pos/neg counts
__global__ void k_label(const float* __restrict__ anchors, const float* __restrict__ gt,
                        const unsigned int* __restrict__ best,
                        unsigned char* packed, unsigned int* blk_cnt) {
    const int img = blockIdx.y;
    __shared__ float sgt[NGT * 4];
    __shared__ unsigned int sbest[NGT];
    __shared__ int wp[4], wn[4];
    const int tid = threadIdx.x;
    if (tid < NGT * 4) sgt[tid] = gt[img * NGT * 4 + tid];
    if (tid < NGT) sbest[tid] = best[img * NGT + tid];
    __syncthreads();
    const int a = blockIdx.x * blockDim.x + tid;
    const bool act = a < A_TOTAL;
    int code = 2;
    if (act) {
        float4 ab = ((const float4*)anchors)[a];
        float mval = -1.f; int arg = 0; bool lq = false;
        #pragma unroll
        for (int g = 0; g < NGT; g++) {
            float v = iou_one(ab.x, ab.y, ab.z, ab.w,
                              sgt[g * 4], sgt[g * 4 + 1], sgt[g * 4 + 2], sgt[g * 4 + 3]);
            if (v > mval) { mval = v; arg = g; }
            if (__float_as_uint(v) == sbest[g] && v > 0.f) lq = true;
        }
        if (lq || mval >= 0.7f) code = 1;
        else if (mval < 0.3f)   code = 0;
        packed[(size_t)img * A_TOTAL + a] = (unsigned char)((code << 5) | arg);
    }
    unsigned long long bp = __ballot(act && code == 1);
    unsigned long long bn = __ballot(act && code == 0);
    const int lane = tid & 63, wid = tid >> 6;
    if (lane == 0) { wp[wid] = __popcll(bp); wn[wid] = __popcll(bn); }
    __syncthreads();
    if (tid == 0) {
        unsigned int p = wp[0] + wp[1] + wp[2] + wp[3];
        unsigned int n = wn[0] + wn[1] + wn[2] + wn[3];
        blk_cnt[img * NBLK + blockIdx.x] = (p << 16) | n;
    }
}

// pass 3a: scan 625 block counts per image (64-bit packed)
__global__ void k_offsets(const unsigned int* __restrict__ blk_cnt,
                          unsigned long long* blk_off,
                          int* pos_total, int* sel_count) {
    const int img = blockIdx.x;
    const int t = threadIdx.x;           // 1024 threads
    __shared__ unsigned long long s[1024];
    unsigned long long c = 0ULL;
    if (t < NBLK) {
        unsigned int u = blk_cnt[img * NBLK + t];
        c = ((unsigned long long)(u >> 16) << 32) | (u & 0xFFFFu);
    }
    s[t] = c;
    __syncthreads();
    #pragma unroll
    for (int off = 1; off < 1024; off <<= 1) {
        unsigned long long add = (t >= off) ? s[t - off] : 0ULL;
        __syncthreads();
        s[t] += add;
        __syncthreads();
    }
    if (t < NBLK) blk_off[img * NBLK + t] = s[t] - c;   // exclusive
    if (t == 1023) {
        unsigned long long tot = s[t];
        int tp = (int)(tot >> 32), tn = (int)(tot & 0xFFFFFFFFu);
        int npos = min(tp, 128);
        int nneg = min(tn, 256 - npos);
        pos_total[img] = tp;
        sel_count[img] = npos + nneg;
    }
}

// pass 3b: write selected anchors to deterministic slots (no atomics)
__global__ void k_select(const unsigned char* __restrict__ packed,
                         const unsigned long long* __restrict__ blk_off,
                         const int* __restrict__ pos_total,
                         int* sel) {
    const int img = blockIdx.y;
    const int t = threadIdx.x;
    const int a = blockIdx.x * 256 + t;
    const bool act = a < A_TOTAL;
    int code = 2;
    if (act) code = packed[(size_t)img * A_TOTAL + a] >> 5;
    const bool isp = act && code == 1;
    const bool isn = act && code == 0;
    unsigned long long bp = __ballot(isp);
    unsigned long long bn = __ballot(isn);
    const int lane = t & 63, wid = t >> 6;
    __shared__ int wtp[4], wtn[4];
    if (lane == 0) { wtp[wid] = __popcll(bp); wtn[wid] = __popcll(bn); }
    __syncthreads();
    const unsigned long long mlt = (1ULL << lane) - 1ULL;
    int rp = __popcll(bp & mlt);
    int rn = __popcll(bn & mlt);
    for (int w = 0; w < 4; w++) {
        if (w < wid) { rp += wtp[w]; rn += wtn[w]; }
    }
    unsigned long long bo = blk_off[img * NBLK + blockIdx.x];
    const int base_p = (int)(bo >> 32), base_n = (int)(bo & 0xFFFFFFFFu);
    const int npos = min(pos_total[img], 128);
    const int capn = 256 - npos;
    if (isp) {
        int r = base_p + rp;
        if (r < npos) sel[img * 256 + r] = a | (1 << 30);
    }
    if (isn) {
        int r = base_n + rn;
        if (r < capn) sel[img * 256 + npos + r] = a;
    }
}

// pass 4a: partial conv — 4 anchors x 64-input-channel chunk per block
__global__ __launch_bounds__(256) void k_conv(
    const float* __restrict__ f0, const float* __restrict__ f1,
    const float* __restrict__ f2, const float* __restrict__ f3,
    const float* __restrict__ f4,
    const float* __restrict__ w_in,
    const int* __restrict__ sel, const int* __restrict__ sel_count,
    float* __restrict__ xpart) {
    const int img = blockIdx.z;
    const int chunk = blockIdx.y;
    const int slot0 = blockIdx.x * ANB;
    const int nsel = sel_count[img];
    if (slot0 >= nsel) return;

    __shared__ __align__(16) float patch[ANB][TERMS];   // 9216 B
    __shared__ int s_W[ANB], s_y[ANB], s_x[ANB], s_act[ANB];
    __shared__ const float* s_fm[ANB];
    const int tid = threadIdx.x;

    if (tid < ANB) {
        int slot = slot0 + tid;
        bool act = slot < nsel;
        int e = act ? sel[img * 256 + slot] : 0;
        int a = e & 0x3FFFFFFF;
        int W, aid, y, x, lvl;
        decode_anchor(a, W, aid, y, x, lvl);
        s_W[tid] = W; s_y[tid] = y; s_x[tid] = x; s_act[tid] = act ? 1 : 0;
        s_fm[tid] = (lvl == 0 ? f0 : lvl == 1 ? f1 : lvl == 2 ? f2 : lvl == 3 ? f3 : f4);
    }
    __syncthreads();

    for (int p = tid; p < ANB * TERMS; p += 256) {
        int aa = p / TERMS;
        int idx = p - aa * TERMS;
        int cil = idx / 9;
        int r = idx - cil * 9;
        int ky = r / 3, kx = r - ky * 3;
        int W = s_W[aa];
        int yy = s_y[aa] + ky - 1, xx = s_x[aa] + kx - 1;
        float v = 0.f;
        if (s_act[aa] && yy >= 0 && yy < W && xx >= 0 && xx < W) {
            const float* fm = s_fm[aa];
            int ci = chunk * CI_PER + cil;
            v = fm[(((size_t)img * 256 + ci) * W + yy) * W + xx];
        }
        patch[aa][idx] = v;
    }
    __syncthreads();

    const int c = tid;
    const float4* wr = (const float4*)(w_in + (size_t)c * 2304 + chunk * TERMS);
    const float4* p0 = (const float4*)patch[0];
    const float4* p1 = (const float4*)patch[1];
    const float4* p2 = (const float4*)patch[2];
    const float4* p3 = (const float4*)patch[3];
    float acc0 = 0.f, acc1 = 0.f, acc2 = 0.f, acc3 = 0.f;
    #pragma unroll 4
    for (int i = 0; i < TERMS / 4; i++) {
        float4 w = wr[i];
        float4 q;
        q = p0[i]; acc0 += w.x * q.x + w.y * q.y + w.z * q.z + w.w * q.w;
        q = p1[i]; acc1 += w.x * q.x + w.y * q.y + w.z * q.z + w.w * q.w;
        q = p2[i]; acc2 += w.x * q.x + w.y * q.y + w.z * q.z + w.w * q.w;
        q = p3[i]; acc3 += w.x * q.x + w.y * q.y + w.z * q.z + w.w * q.w;
    }
    float acc[ANB] = {acc0, acc1, acc2, acc3};
    #pragma unroll
    for (int aa = 0; aa < ANB; aa++) {
        int slot = slot0 + aa;
        if (slot < nsel)
            xpart[(((size_t)img * CHUNKS + chunk) * 256 + slot) * 256 + c] = acc[aa];
    }
}

// pass 4b: reduce chunks + bias + relu, 5 block-dots, per-anchor losses
__global__ __launch_bounds__(256) void k_post(
    const float* __restrict__ xpart,
    const float* __restrict__ anchors, const float* __restrict__ gt,
    const float* __restrict__ b_in,
    const float* __restrict__ w_obj, const float* __restrict__ b_obj,
    const float* __restrict__ w_del, const float* __restrict__ b_del,
    const unsigned char* __restrict__ packed,
    const int* __restrict__ sel, const int* __restrict__ sel_count,
    float* __restrict__ lossbuf) {
    const int img = blockIdx.y;
    const int slot = blockIdx.x;
    const int nsel = sel_count[img];
    if (slot >= nsel) return;
    const int e = sel[img * 256 + slot];
    const int is_pos = (e >> 30) & 1;
    const int a = e & 0x3FFFFFFF;
    int W, aid, y, x, lvl;
    decode_anchor(a, W, aid, y, x, lvl);

    const int c = threadIdx.x;
    float s = b_in[c];
    #pragma unroll
    for (int ch = 0; ch < CHUNKS; ch++)
        s += xpart[(((size_t)img * CHUNKS + ch) * 256 + slot) * 256 + c];
    float xf = fmaxf(s, 0.f);

    float part[5];
    part[0] = xf * w_obj[aid * 256 + c];
    #pragma unroll
    for (int j = 0; j < 4; j++) part[1 + j] = xf * w_del[(aid * 4 + j) * 256 + c];
    const int lane = c & 63, wid = c >> 6;
    __shared__ float red[5][4];
    #pragma unroll
    for (int o = 32; o > 0; o >>= 1)
        #pragma unroll
        for (int j = 0; j < 5; j++) part[j] += __shfl_down(part[j], o);
    if (lane == 0)
        #pragma unroll
        for (int j = 0; j < 5; j++) red[j][wid] = part[j];
    __syncthreads();

    if (c == 0) {
        float logit = red[0][0] + red[0][1] + red[0][2] + red[0][3] + b_obj[aid];
        float tgt = is_pos ? 1.f : 0.f;
        float bce = fmaxf(logit, 0.f) - logit * tgt + log1pf(expf(-fabsf(logit)));
        float l1 = 0.f;
        if (is_pos) {
            float d[4];
            #pragma unroll
            for (int j = 0; j < 4; j++)
                d[j] = red[1 + j][0] + red[1 + j][1] + red[1 + j][2] + red[1 + j][3] + b_del[aid * 4 + j];
            int m = packed[(size_t)img * A_TOTAL + a] & 31;
            const float* sp = anchors + (size_t)a * 4;
            const float* t = gt + (size_t)(img * NGT + m) * 4;
            float sw = sp[2] - sp[0], sh = sp[3] - sp[1];
            float scx = sp[0] + 0.5f * sw, scy = sp[1] + 0.5f * sh;
            float tw = t[2] - t[0], th = t[3] - t[1];
            float tcx = t[0] + 0.5f * tw, tcy = t[1] + 0.5f * th;
            float g0 = (tcx - scx) / sw, g1 = (tcy - scy) / sh;
            float g2 = logf(tw / sw),    g3 = logf(th / sh);
            l1 = fabsf(d[0] - g0) + fabsf(d[1] - g1) + fabsf(d[2] - g2) + fabsf(d[3] - g3);
        }
        lossbuf[(img * 256 + slot) * 2 + 0] = bce;
        lossbuf[(img * 256 + slot) * 2 + 1] = l1;
    }
}

// pass 5: deterministic tree-sum of per-anchor losses -> out[2]
__global__ void k_final(const float* __restrict__ lossbuf,
                        const int* __restrict__ sel_count,
                        float* __restrict__ out) {
    const int t = threadIdx.x;      // 512 threads
    const int img = t >> 8, slot = t & 255;
    float bce = 0.f, l1 = 0.f;
    if (slot < sel_count[img]) {
        bce = lossbuf[t * 2 + 0];
        l1  = lossbuf[t * 2 + 1];
    }
    const int lane = t & 63, wid = t >> 6;
    #pragma unroll
    for (int o = 32; o > 0; o >>= 1) {
        bce += __shfl_down(bce, o);
        l1  += __shfl_down(l1, o);
    }
    __shared__ float rb[8], rl[8];
    if (lane == 0) { rb[wid] = bce; rl[wid] = l1; }
    __syncthreads();
    if (t == 0) {
        float sb = 0.f, sl = 0.f;
        #pragma unroll
        for (int w = 0; w < 8; w++) { sb += rb[w]; sl += rl[w]; }
        out[0] = 0.5f * sb;
        out[1] = 0.5f * sl;
    }
}

// fallback monolithic eval (round-3 proven) if workspace is too small
__global__ __launch_bounds__(256) void k_eval(
    const float* __restrict__ f0, const float* __restrict__ f1,
    const float* __restrict__ f2, const float* __restrict__ f3,
    const float* __restrict__ f4,
    const float* __restrict__ anchors, const float* __restrict__ gt,
    const float* __restrict__ w_in, const float* __restrict__ b_in,
    const float* __restrict__ w_obj, const float* __restrict__ b_obj,
    const float* __restrict__ w_del, const float* __restrict__ b_del,
    const unsigned char* __restrict__ packed,
    const int* __restrict__ sel, const int* __restrict__ sel_count,
    float* out) {
    const int img = blockIdx.x >> 6;
    const int slot0 = (blockIdx.x & 63) * 4;
    const int nsel = sel_count[img];
    if (slot0 >= nsel) return;

    __shared__ __align__(16) float patch[4][2304];
    __shared__ float red[4][5][4];
    __shared__ float lsum[2];
    const int c = threadIdx.x;
    if (c < 2) lsum[c] = 0.f;

    bool actv[4]; int av[4], aidv[4], isposv[4];
    #pragma unroll
    for (int aa = 0; aa < 4; aa++) {
        int slot = slot0 + aa;
        bool act = slot < nsel;
        actv[aa] = act;
        int e = act ? sel[img * 256 + slot] : 0;
        isposv[aa] = (e >> 30) & 1;
        int a = e & 0x3FFFFFFF;
        av[aa] = a;
        int W, aid, y, x, lvl;
        decode_anchor(a, W, aid, y, x, lvl);
        aidv[aa] = aid;
        const float* fm = lvl == 0 ? f0 : lvl == 1 ? f1 : lvl == 2 ? f2 : lvl == 3 ? f3 : f4;
        const float* ch = fm + ((size_t)img * 256 + c) * W * W;
        #pragma unroll
        for (int ky = 0; ky < 3; ky++)
            #pragma unroll
            for (int kx = 0; kx < 3; kx++) {
                int yy = y + ky - 1, xx = x + kx - 1;
                float v = (act && yy >= 0 && yy < W && xx >= 0 && xx < W) ? ch[yy * W + xx] : 0.f;
                patch[aa][c * 9 + ky * 3 + kx] = v;
            }
    }
    __syncthreads();

    const float bi = b_in[c];
    float acc0 = bi, acc1 = bi, acc2 = bi, acc3 = bi;
    const float4* wr = (const float4*)(w_in + (size_t)c * 2304);
    const float4* p0 = (const float4*)patch[0];
    const float4* p1 = (const float4*)patch[1];
    const float4* p2 = (const float4*)patch[2];
    const float4* p3 = (const float4*)patch[3];
    #pragma unroll 4
    for (int i = 0; i < 576; i++) {
        float4 w = wr[i];
        float4 q;
        q = p0[i]; acc0 += w.x * q.x + w.y * q.y + w.z * q.z + w.w * q.w;
        q = p1[i]; acc1 += w.x * q.x + w.y * q.y + w.z * q.z + w.w * q.w;
        q = p2[i]; acc2 += w.x * q.x + w.y * q.y + w.z * q.z + w.w * q.w;
        q = p3[i]; acc3 += w.x * q.x + w.y * q.y + w.z * q.z + w.w * q.w;
    }
    float xf[4] = { fmaxf(acc0, 0.f), fmaxf(acc1, 0.f), fmaxf(acc2, 0.f), fmaxf(acc3, 0.f) };

    float part[4][5];
    #pragma unroll
    for (int aa = 0; aa < 4; aa++) {
        part[aa][0] = xf[aa] * w_obj[aidv[aa] * 256 + c];
        #pragma unroll
        for (int j = 0; j < 4; j++)
            part[aa][1 + j] = xf[aa] * w_del[(aidv[aa] * 4 + j) * 256 + c];
    }
    const int lane = c & 63, wid = c >> 6;
    #pragma unroll
    for (int o = 32; o > 0; o >>= 1)
        #pragma unroll
        for (int aa = 0; aa < 4; aa++)
            #pragma unroll
            for (int j = 0; j < 5; j++)
                part[aa][j] += __shfl_down(part[aa][j], o);
    if (lane == 0)
        #pragma unroll
        for (int aa = 0; aa < 4; aa++)
            #pragma unroll
            for (int j = 0; j < 5; j++)
                red[aa][j][wid] = part[aa][j];
    __syncthreads();

    if (c < 4 && actv[c]) {
        const int aa = c;
        float logit = red[aa][0][0] + red[aa][0][1] + red[aa][0][2] + red[aa][0][3] + b_obj[aidv[aa]];
        float tgt = isposv[aa] ? 1.f : 0.f;
        float bce = fmaxf(logit, 0.f) - logit * tgt + log1pf(expf(-fabsf(logit)));
        atomicAdd(&lsum[0], bce);
        if (isposv[aa]) {
            float d[4];
            #pragma unroll
            for (int j = 0; j < 4; j++)
                d[j] = red[aa][1 + j][0] + red[aa][1 + j][1] + red[aa][1 + j][2] + red[aa][1 + j][3]
                       + b_del[aidv[aa] * 4 + j];
            int a = av[aa];
            int m = packed[(size_t)img * A_TOTAL + a] & 31;
            const float* s = anchors + (size_t)a * 4;
            const float* t = gt + (size_t)(img * NGT + m) * 4;
            float sw = s[2] - s[0], sh = s[3] - s[1];
            float scx = s[0] + 0.5f * sw, scy = s[1] + 0.5f * sh;
            float tw = t[2] - t[0], th = t[3] - t[1];
            float tcx = t[0] + 0.5f * tw, tcy = t[1] + 0.5f * th;
            float g0 = (tcx - scx) / sw, g1 = (tcy - scy) / sh;
            float g2 = logf(tw / sw),    g3 = logf(th / sh);
            float l1 = fabsf(d[0] - g0) + fabsf(d[1] - g1) + fabsf(d[2] - g2) + fabsf(d[3] - g3);
            atomicAdd(&lsum[1], l1);
        }
    }
    __syncthreads();
    if (c == 0) {
        atomicAdd(&out[0], 0.5f * lsum[0]);
        atomicAdd(&out[1], 0.5f * lsum[1]);
    }
}

extern "C" void kernel_launch(void* const* d_in, const int* in_sizes, int n_in,
                              void* d_out, int out_size, void* d_ws, size_t ws_size,
                              hipStream_t stream) {
    const float* f_p6 = (const float*)d_in[0];
    const float* f_p5 = (const float*)d_in[1];
    const float* f_p4 = (const float*)d_in[2];
    const float* f_p3 = (const float*)d_in[3];
    const float* f_p2 = (const float*)d_in[4];
    const float* anchors = (const float*)d_in[5];
    const float* gt      = (const float*)d_in[6];
    const float* w_in  = (const float*)d_in[7];
    const float* b_in  = (const float*)d_in[8];
    const float* w_obj = (const float*)d_in[9];
    const float* b_obj = (const float*)d_in[10];
    const float* w_del = (const float*)d_in[11];
    const float* b_del = (const float*)d_in[12];

    // workspace layout
    char* ws = (char*)d_ws;
    unsigned int* best          = (unsigned int*)(ws + 0);        // 160 B
    int* pos_total              = (int*)(ws + 160);               // 8 B
    int* sel_count              = (int*)(ws + 168);               // 8 B
    int* sel                    = (int*)(ws + 192);               // 2048 B
    unsigned int* blk_cnt       = (unsigned int*)(ws + 2240);     // 5000 B
    unsigned long long* blk_off = (unsigned long long*)(ws + 7296); // 10000 B
    unsigned char* packed       = (unsigned char*)(ws + 17344);   // 319764 B -> 337108
    float* lossbuf              = (float*)(ws + 337152);          // 4096 B  -> 341248
    float* xpart                = (float*)(ws + 341248);          // 2097152 -> 2438400
    float* pmax                 = (float*)(ws + 341248);          // OVERLAY on xpart:
    // pmax (2*625*20*4 = 100000 B) is written by k_bmax and consumed by k_bred
    // BEFORE k_conv writes xpart — disjoint lifetimes, no extra workspace.
    const size_t WS_NEEDED = 2438400;

    float* out = (float*)d_out;

    k_init<<<1, 64, 0, stream>>>(best, out);

    if (ws_size >= WS_NEEDED) {
        k_bmax<<<dim3(NBLK, 2), 256, 0, stream>>>(anchors, gt, pmax);
        k_bred<<<dim3(NGT, 2), 256, 0, stream>>>(pmax, best);
        k_label<<<dim3(NBLK, 2), 256, 0, stream>>>(anchors, gt, best, packed, blk_cnt);
        k_offsets<<<2, 1024, 0, stream>>>(blk_cnt, blk_off, pos_total, sel_count);
        k_select<<<dim3(NBLK, 2), 256, 0, stream>>>(packed, blk_off, pos_total, sel);
        k_conv<<<dim3(64, CHUNKS, 2), 256, 0, stream>>>(f_p6, f_p5, f_p4, f_p3, f_p2,
                                                        w_in, sel, sel_count, xpart);
        k_post<<<dim3(256, 2), 256, 0, stream>>>(xpart, anchors, gt, b_in,
                                                 w_obj, b_obj, w_del, b_del,
                                                 packed, sel, sel_count, lossbuf);
        k_final<<<1, 512, 0, stream>>>(lossbuf, sel_count, out);
    } else {
        k_best<<<dim3(64, 2), 256, 0, stream>>>(anchors, gt, best);
        k_label<<<dim3(NBLK, 2), 256, 0, stream>>>(anchors, gt, best, packed, blk_cnt);
        k_offsets<<<2, 1024, 0, stream>>>(blk_cnt, blk_off, pos_total, sel_count);
        k_select<<<dim3(NBLK, 2), 256, 0, stream>>>(packed, blk_off, pos_total, sel);
        k_eval<<<128, 256, 0, stream>>>(f_p6, f_p5, f_p4, f_p3, f_p2,
                                        anchors, gt, w_in, b_in, w_obj, b_obj,
                                        w_del, b_del, packed, sel, sel_count, out);
    }
}

// Round 6
// 80.124 us; speedup vs baseline: 11.9841x; 1.0988x over previous
//
#include <hip/hip_runtime.h>
#include <hip/hip_bf16.h>
#include <math.h>

#define A_TOTAL 159882
#define NGT 20
#define NBLK 625   // ceil(A_TOTAL/256)
#define ANB 4      // anchors per conv block

// level geometry: p6(13) p5(25) p4(50) p3(100) p2(200), 3 anchors/pos
// cumulative anchor offsets: 0, 507, 2382, 9882, 39882, 159882

__device__ __forceinline__ float iou_one(float ax1, float ay1, float ax2, float ay2,
                                         float gx1, float gy1, float gx2, float gy2) {
    float a1 = (ax2 - ax1) * (ay2 - ay1);
    float a2 = (gx2 - gx1) * (gy2 - gy1);
    float ltx = fmaxf(ax1, gx1), lty = fmaxf(ay1, gy1);
    float rbx = fminf(ax2, gx2), rby = fminf(ay2, gy2);
    float w = fmaxf(rbx - ltx, 0.f), h = fmaxf(rby - lty, 0.f);
    float inter = w * h;
    return inter / (a1 + a2 - inter);
}

__device__ __forceinline__ void decode_anchor(int a, int& W, int& aid, int& y, int& x, int& lvl) {
    int off;
    if      (a < 507)   { off = 0;     W = 13;  lvl = 0; }
    else if (a < 2382)  { off = 507;   W = 25;  lvl = 1; }
    else if (a < 9882)  { off = 2382;  W = 50;  lvl = 2; }
    else if (a < 39882) { off = 9882;  W = 100; lvl = 3; }
    else                { off = 39882; W = 200; lvl = 4; }
    int rel = a - off;
    aid = rel % 3;
    int pos = rel / 3;
    y = pos / W; x = pos % W;
}

__global__ void k_init(unsigned int* best, float* out) {
    int t = threadIdx.x;
    if (t < 2 * NGT) best[t] = 0u;
    if (t < 2) out[t] = 0.f;
}

// pass 1a: per-block column maxes of the IoU matrix (full grid, no atomics)
__global__ __launch_bounds__(256) void k_bmax(const float* __restrict__ anchors,
                                              const float* __restrict__ gt,
                                              float* __restrict__ pmax) {
    const int img = blockIdx.y;
    __shared__ float sgt[NGT * 4];
    __shared__ float sred[4][NGT];
    const int tid = threadIdx.x;
    if (tid < NGT * 4) sgt[tid] = gt[img * NGT * 4 + tid];
    __syncthreads();
    const int a = blockIdx.x * 256 + tid;
    float4 ab = make_float4(0.f, 0.f, 1.f, 1.f);
    if (a < A_TOTAL) ab = ((const float4*)anchors)[a];
    const int lane = tid & 63, wid = tid >> 6;
    #pragma unroll
    for (int g = 0; g < NGT; g++) {
        float u = (a < A_TOTAL)
                    ? iou_one(ab.x, ab.y, ab.z, ab.w,
                              sgt[g * 4], sgt[g * 4 + 1], sgt[g * 4 + 2], sgt[g * 4 + 3])
                    : 0.f;
        #pragma unroll
        for (int o = 32; o > 0; o >>= 1) u = fmaxf(u, __shfl_down(u, o));
        if (lane == 0) sred[wid][g] = u;
    }
    __syncthreads();
    if (tid < NGT) {
        float u = fmaxf(fmaxf(sred[0][tid], sred[1][tid]),
                        fmaxf(sred[2][tid], sred[3][tid]));
        pmax[((size_t)img * NBLK + blockIdx.x) * NGT + tid] = u;
    }
}

// pass 1b: tree-reduce 625 partials per (img, gt) -> best (plain store)
__global__ void k_bred(const float* __restrict__ pmax, unsigned int* __restrict__ best) {
    const int g = blockIdx.x, img = blockIdx.y;
    const int tid = threadIdx.x;   // 256
    float v = 0.f;
    for (int i = tid; i < NBLK; i += 256)
        v = fmaxf(v, pmax[((size_t)img * NBLK + i) * NGT + g]);
    const int lane = tid & 63, wid = tid >> 6;
    #pragma unroll
    for (int o = 32; o > 0; o >>= 1) v = fmaxf(v, __shfl_down(v, o));
    __shared__ float r[4];
    if (lane == 0) r[wid] = v;
    __syncthreads();
    if (tid == 0)
        best[img * NGT + g] = __float_as_uint(fmaxf(fmaxf(r[0], r[1]), fmaxf(r[2], r[3])));
}

// fallback pass 1 (round-2 proven): register running max + 20 atomics/block
__global__ void k_best(const float* __restrict__ anchors, const float* __restrict__ gt,
                       unsigned int* best) {
    const int img = blockIdx.y;
    __shared__ float sgt[NGT * 4];
    __shared__ float sred[4][NGT];
    const int tid = threadIdx.x;
    if (tid < NGT * 4) sgt[tid] = gt[img * NGT * 4 + tid];
    __syncthreads();
    float vmax[NGT];
    #pragma unroll
    for (int g = 0; g < NGT; g++) vmax[g] = 0.f;
    const int stride = gridDim.x * blockDim.x;
    for (int a = blockIdx.x * blockDim.x + tid; a < A_TOTAL; a += stride) {
        float4 ab = ((const float4*)anchors)[a];
        #pragma unroll
        for (int g = 0; g < NGT; g++) {
            float v = iou_one(ab.x, ab.y, ab.z, ab.w,
                              sgt[g * 4], sgt[g * 4 + 1], sgt[g * 4 + 2], sgt[g * 4 + 3]);
            vmax[g] = fmaxf(vmax[g], v);
        }
    }
    const int lane = tid & 63, wid = tid >> 6;
    #pragma unroll
    for (int g = 0; g < NGT; g++) {
        float v = vmax[g];
        #pragma unroll
        for (int o = 32; o > 0; o >>= 1) v = fmaxf(v, __shfl_down(v, o));
        if (lane == 0) sred[wid][g] = v;
    }
    __syncthreads();
    if (tid < NGT) {
        float v = fmaxf(fmaxf(sred[0][tid], sred[1][tid]),
                        fmaxf(sred[2][tid], sred[3][tid]));
        atomicMax(&best[img * NGT + tid], __float_as_uint(v));
    }
}

// pass 2: labels + matched gt packed into a byte; per-block pos/neg counts
__global__ void k_label(const float* __restrict__ anchors, const float* __restrict__ gt,
                        const unsigned int* __restrict__ best,
                        unsigned char* packed, unsigned int* blk_cnt) {
    const int img = blockIdx.y;
    __shared__ float sgt[NGT * 4];
    __shared__ unsigned int sbest[NGT];
    __shared__ int wp[4], wn[4];
    const int tid = threadIdx.x;
    if (tid < NGT * 4) sgt[tid] = gt[img * NGT * 4 + tid];
    if (tid < NGT) sbest[tid] = best[img * NGT + tid];
    __syncthreads();
    const int a = blockIdx.x * blockDim.x + tid;
    const bool act = a < A_TOTAL;
    int code = 2;
    if (act) {
        float4 ab = ((const float4*)anchors)[a];
        float mval = -1.f; int arg = 0; bool lq = false;
        #pragma unroll
        for (int g = 0; g < NGT; g++) {
            float v = iou_one(ab.x, ab.y, ab.z, ab.w,
                              sgt[g * 4], sgt[g * 4 + 1], sgt[g * 4 + 2], sgt[g * 4 + 3]);
            if (v > mval) { mval = v; arg = g; }
            if (__float_as_uint(v) == sbest[g] && v > 0.f) lq = true;
        }
        if (lq || mval >= 0.7f) code = 1;
        else if (mval < 0.3f)   code = 0;
        packed[(size_t)img * A_TOTAL + a] = (unsigned char)((code << 5) | arg);
    }
    unsigned long long bp = __ballot(act && code == 1);
    unsigned long long bn = __ballot(act && code == 0);
    const int lane = tid & 63, wid = tid >> 6;
    if (lane == 0) { wp[wid] = __popcll(bp); wn[wid] = __popcll(bn); }
    __syncthreads();
    if (tid == 0) {
        unsigned int p = wp[0] + wp[1] + wp[2] + wp[3];
        unsigned int n = wn[0] + wn[1] + wn[2] + wn[3];
        blk_cnt[img * NBLK + blockIdx.x] = (p << 16) | n;
    }
}

// pass 3a: scan 625 block counts per image (shfl two-level scan, 2 barriers)
__global__ void k_offsets(const unsigned int* __restrict__ blk_cnt,
                          unsigned long long* blk_off,
                          int* pos_total, int* sel_count) {
    const int img = blockIdx.x;
    const int t = threadIdx.x;           // 1024 threads
    const int lane = t & 63, wid = t >> 6;
    unsigned long long c = 0ULL;
    if (t < NBLK) {
        unsigned int u = blk_cnt[img * NBLK + t];
        c = ((unsigned long long)(u >> 16) << 32) | (u & 0xFFFFu);
    }
    unsigned long long v = c;
    #pragma unroll
    for (int off = 1; off < 64; off <<= 1) {
        unsigned long long u = __shfl_up(v, off);
        if (lane >= off) v += u;
    }
    __shared__ unsigned long long wsum[16];
    if (lane == 63) wsum[wid] = v;
    __syncthreads();
    if (wid == 0) {
        unsigned long long w = (lane < 16) ? wsum[lane] : 0ULL;
        #pragma unroll
        for (int off = 1; off < 16; off <<= 1) {
            unsigned long long u = __shfl_up(w, off);
            if (lane >= off) w += u;
        }
        if (lane < 16) wsum[lane] = w;   // inclusive wave prefix
    }
    __syncthreads();
    unsigned long long excl = v - c + (wid > 0 ? wsum[wid - 1] : 0ULL);
    if (t < NBLK) blk_off[img * NBLK + t] = excl;
    if (t == 1023) {
        unsigned long long tot = wsum[15];
        int tp = (int)(tot >> 32), tn = (int)(tot & 0xFFFFFFFFu);
        int npos = min(tp, 128);
        int nneg = min(tn, 256 - npos);
        pos_total[img] = tp;
        sel_count[img] = npos + nneg;
    }
}

// pass 3b: write selected anchors to deterministic slots (no atomics)
__global__ void k_select(const unsigned char* __restrict__ packed,
                         const unsigned long long* __restrict__ blk_off,
                         const int* __restrict__ pos_total,
                         int* sel) {
    const int img = blockIdx.y;
    const int t = threadIdx.x;
    const int a = blockIdx.x * 256 + t;
    const bool act = a < A_TOTAL;
    int code = 2;
    if (act) code = packed[(size_t)img * A_TOTAL + a] >> 5;
    const bool isp = act && code == 1;
    const bool isn = act && code == 0;
    unsigned long long bp = __ballot(isp);
    unsigned long long bn = __ballot(isn);
    const int lane = t & 63, wid = t >> 6;
    __shared__ int wtp[4], wtn[4];
    if (lane == 0) { wtp[wid] = __popcll(bp); wtn[wid] = __popcll(bn); }
    __syncthreads();
    const unsigned long long mlt = (1ULL << lane) - 1ULL;
    int rp = __popcll(bp & mlt);
    int rn = __popcll(bn & mlt);
    for (int w = 0; w < 4; w++) {
        if (w < wid) { rp += wtp[w]; rn += wtn[w]; }
    }
    unsigned long long bo = blk_off[img * NBLK + blockIdx.x];
    const int base_p = (int)(bo >> 32), base_n = (int)(bo & 0xFFFFFFFFu);
    const int npos = min(pos_total[img], 128);
    const int capn = 256 - npos;
    if (isp) {
        int r = base_p + rp;
        if (r < npos) sel[img * 256 + r] = a | (1 << 30);
    }
    if (isn) {
        int r = base_n + rn;
        if (r < capn) sel[img * 256 + npos + r] = a;
    }
}

// pass 4a: partial conv — ANB anchors x (256/NCH)-input-channel chunk per block
template <int NCH>
__global__ __launch_bounds__(256) void k_conv(
    const float* __restrict__ f0, const float* __restrict__ f1,
    const float* __restrict__ f2, const float* __restrict__ f3,
    const float* __restrict__ f4,
    const float* __restrict__ w_in,
    const int* __restrict__ sel, const int* __restrict__ sel_count,
    float* __restrict__ xpart) {
    constexpr int CIP = 256 / NCH;
    constexpr int TRM = CIP * 9;
    const int img = blockIdx.z;
    const int chunk = blockIdx.y;
    const int slot0 = blockIdx.x * ANB;
    const int nsel = sel_count[img];
    if (slot0 >= nsel) return;

    __shared__ __align__(16) float patch[ANB][TRM];
    __shared__ int s_W[ANB], s_y[ANB], s_x[ANB], s_act[ANB];
    __shared__ const float* s_fm[ANB];
    const int tid = threadIdx.x;

    if (tid < ANB) {
        int slot = slot0 + tid;
        bool act = slot < nsel;
        int e = act ? sel[img * 256 + slot] : 0;
        int a = e & 0x3FFFFFFF;
        int W, aid, y, x, lvl;
        decode_anchor(a, W, aid, y, x, lvl);
        s_W[tid] = W; s_y[tid] = y; s_x[tid] = x; s_act[tid] = act ? 1 : 0;
        s_fm[tid] = (lvl == 0 ? f0 : lvl == 1 ? f1 : lvl == 2 ? f2 : lvl == 3 ? f3 : f4);
    }
    __syncthreads();

    for (int p = tid; p < ANB * TRM; p += 256) {
        int aa = p / TRM;
        int idx = p - aa * TRM;
        int cil = idx / 9;
        int r = idx - cil * 9;
        int ky = r / 3, kx = r - ky * 3;
        int W = s_W[aa];
        int yy = s_y[aa] + ky - 1, xx = s_x[aa] + kx - 1;
        float v = 0.f;
        if (s_act[aa] && yy >= 0 && yy < W && xx >= 0 && xx < W) {
            const float* fm = s_fm[aa];
            int ci = chunk * CIP + cil;
            v = fm[(((size_t)img * 256 + ci) * W + yy) * W + xx];
        }
        patch[aa][idx] = v;
    }
    __syncthreads();

    const int c = tid;
    const float4* wr = (const float4*)(w_in + (size_t)c * 2304 + chunk * TRM);
    const float4* p0 = (const float4*)patch[0];
    const float4* p1 = (const float4*)patch[1];
    const float4* p2 = (const float4*)patch[2];
    const float4* p3 = (const float4*)patch[3];
    float acc0 = 0.f, acc1 = 0.f, acc2 = 0.f, acc3 = 0.f;
    #pragma unroll 8
    for (int i = 0; i < TRM / 4; i++) {
        float4 w = wr[i];
        float4 q;
        q = p0[i]; acc0 += w.x * q.x + w.y * q.y + w.z * q.z + w.w * q.w;
        q = p1[i]; acc1 += w.x * q.x + w.y * q.y + w.z * q.z + w.w * q.w;
        q = p2[i]; acc2 += w.x * q.x + w.y * q.y + w.z * q.z + w.w * q.w;
        q = p3[i]; acc3 += w.x * q.x + w.y * q.y + w.z * q.z + w.w * q.w;
    }
    float acc[ANB] = {acc0, acc1, acc2, acc3};
    #pragma unroll
    for (int aa = 0; aa < ANB; aa++) {
        int slot = slot0 + aa;
        if (slot < nsel)
            xpart[(((size_t)img * NCH + chunk) * 256 + slot) * 256 + c] = acc[aa];
    }
}

// pass 4b: reduce chunks + bias + relu, 5 block-dots, per-anchor losses
template <int NCH>
__global__ __launch_bounds__(256) void k_post(
    const float* __restrict__ xpart,
    const float* __restrict__ anchors, const float* __restrict__ gt,
    const float* __restrict__ b_in,
    const float* __restrict__ w_obj, const float* __restrict__ b_obj,
    const float* __restrict__ w_del, const float* __restrict__ b_del,
    const unsigned char* __restrict__ packed,
    const int* __restrict__ sel, const int* __restrict__ sel_count,
    float* __restrict__ lossbuf) {
    const int img = blockIdx.y;
    const int slot = blockIdx.x;
    const int nsel = sel_count[img];
    if (slot >= nsel) return;
    const int e = sel[img * 256 + slot];
    const int is_pos = (e >> 30) & 1;
    const int a = e & 0x3FFFFFFF;
    int W, aid, y, x, lvl;
    decode_anchor(a, W, aid, y, x, lvl);

    const int c = threadIdx.x;
    float s = b_in[c];
    #pragma unroll
    for (int ch = 0; ch < NCH; ch++)
        s += xpart[(((size_t)img * NCH + ch) * 256 + slot) * 256 + c];
    float xf = fmaxf(s, 0.f);

    float part[5];
    part[0] = xf * w_obj[aid * 256 + c];
    #pragma unroll
    for (int j = 0; j < 4; j++) part[1 + j] = xf * w_del[(aid * 4 + j) * 256 + c];
    const int lane = c & 63, wid = c >> 6;
    __shared__ float red[5][4];
    #pragma unroll
    for (int o = 32; o > 0; o >>= 1)
        #pragma unroll
        for (int j = 0; j < 5; j++) part[j] += __shfl_down(part[j], o);
    if (lane == 0)
        #pragma unroll
        for (int j = 0; j < 5; j++) red[j][wid] = part[j];
    __syncthreads();

    if (c == 0) {
        float logit = red[0][0] + red[0][1] + red[0][2] + red[0][3] + b_obj[aid];
        float tgt = is_pos ? 1.f : 0.f;
        float bce = fmaxf(logit, 0.f) - logit * tgt + log1pf(expf(-fabsf(logit)));
        float l1 = 0.f;
        if (is_pos) {
            float d[4];
            #pragma unroll
            for (int j = 0; j < 4; j++)
                d[j] = red[1 + j][0] + red[1 + j][1] + red[1 + j][2] + red[1 + j][3] + b_del[aid * 4 + j];
            int m = packed[(size_t)img * A_TOTAL + a] & 31;
            const float* sp = anchors + (size_t)a * 4;
            const float* t = gt + (size_t)(img * NGT + m) * 4;
            float sw = sp[2] - sp[0], sh = sp[3] - sp[1];
            float scx = sp[0] + 0.5f * sw, scy = sp[1] + 0.5f * sh;
            float tw = t[2] - t[0], th = t[3] - t[1];
            float tcx = t[0] + 0.5f * tw, tcy = t[1] + 0.5f * th;
            float g0 = (tcx - scx) / sw, g1 = (tcy - scy) / sh;
            float g2 = logf(tw / sw),    g3 = logf(th / sh);
            l1 = fabsf(d[0] - g0) + fabsf(d[1] - g1) + fabsf(d[2] - g2) + fabsf(d[3] - g3);
        }
        lossbuf[(img * 256 + slot) * 2 + 0] = bce;
        lossbuf[(img * 256 + slot) * 2 + 1] = l1;
    }
}

// pass 5: deterministic tree-sum of per-anchor losses -> out[2]
__global__ void k_final(const float* __restrict__ lossbuf,
                        const int* __restrict__ sel_count,
                        float* __restrict__ out) {
    const int t = threadIdx.x;      // 512 threads
    const int img = t >> 8, slot = t & 255;
    float bce = 0.f, l1 = 0.f;
    if (slot < sel_count[img]) {
        bce = lossbuf[t * 2 + 0];
        l1  = lossbuf[t * 2 + 1];
    }
    const int lane = t & 63, wid = t >> 6;
    #pragma unroll
    for (int o = 32; o > 0; o >>= 1) {
        bce += __shfl_down(bce, o);
        l1  += __shfl_down(l1, o);
    }
    __shared__ float rb[8], rl[8];
    if (lane == 0) { rb[wid] = bce; rl[wid] = l1; }
    __syncthreads();
    if (t == 0) {
        float sb = 0.f, sl = 0.f;
        #pragma unroll
        for (int w = 0; w < 8; w++) { sb += rb[w]; sl += rl[w]; }
        out[0] = 0.5f * sb;
        out[1] = 0.5f * sl;
    }
}

// fallback monolithic eval (round-3 proven) if workspace is too small
__global__ __launch_bounds__(256) void k_eval(
    const float* __restrict__ f0, const float* __restrict__ f1,
    const float* __restrict__ f2, const float* __restrict__ f3,
    const float* __restrict__ f4,
    const float* __restrict__ anchors, const float* __restrict__ gt,
    const float* __restrict__ w_in, const float* __restrict__ b_in,
    const float* __restrict__ w_obj, const float* __restrict__ b_obj,
    const float* __restrict__ w_del, const float* __restrict__ b_del,
    const unsigned char* __restrict__ packed,
    const int* __restrict__ sel, const int* __restrict__ sel_count,
    float* out) {
    const int img = blockIdx.x >> 6;
    const int slot0 = (blockIdx.x & 63) * 4;
    const int nsel = sel_count[img];
    if (slot0 >= nsel) return;

    __shared__ __align__(16) float patch[4][2304];
    __shared__ float red[4][5][4];
    __shared__ float lsum[2];
    const int c = threadIdx.x;
    if (c < 2) lsum[c] = 0.f;

    bool actv[4]; int av[4], aidv[4], isposv[4];
    #pragma unroll
    for (int aa = 0; aa < 4; aa++) {
        int slot = slot0 + aa;
        bool act = slot < nsel;
        actv[aa] = act;
        int e = act ? sel[img * 256 + slot] : 0;
        isposv[aa] = (e >> 30) & 1;
        int a = e & 0x3FFFFFFF;
        av[aa] = a;
        int W, aid, y, x, lvl;
        decode_anchor(a, W, aid, y, x, lvl);
        aidv[aa] = aid;
        const float* fm = lvl == 0 ? f0 : lvl == 1 ? f1 : lvl == 2 ? f2 : lvl == 3 ? f3 : f4;
        const float* ch = fm + ((size_t)img * 256 + c) * W * W;
        #pragma unroll
        for (int ky = 0; ky < 3; ky++)
            #pragma unroll
            for (int kx = 0; kx < 3; kx++) {
                int yy = y + ky - 1, xx = x + kx - 1;
                float v = (act && yy >= 0 && yy < W && xx >= 0 && xx < W) ? ch[yy * W + xx] : 0.f;
                patch[aa][c * 9 + ky * 3 + kx] = v;
            }
    }
    __syncthreads();

    const float bi = b_in[c];
    float acc0 = bi, acc1 = bi, acc2 = bi, acc3 = bi;
    const float4* wr = (const float4*)(w_in + (size_t)c * 2304);
    const float4* p0 = (const float4*)patch[0];
    const float4* p1 = (const float4*)patch[1];
    const float4* p2 = (const float4*)patch[2];
    const float4* p3 = (const float4*)patch[3];
    #pragma unroll 4
    for (int i = 0; i < 576; i++) {
        float4 w = wr[i];
        float4 q;
        q = p0[i]; acc0 += w.x * q.x + w.y * q.y + w.z * q.z + w.w * q.w;
        q = p1[i]; acc1 += w.x * q.x + w.y * q.y + w.z * q.z + w.w * q.w;
        q = p2[i]; acc2 += w.x * q.x + w.y * q.y + w.z * q.z + w.w * q.w;
        q = p3[i]; acc3 += w.x * q.x + w.y * q.y + w.z * q.z + w.w * q.w;
    }
    float xf[4] = { fmaxf(acc0, 0.f), fmaxf(acc1, 0.f), fmaxf(acc2, 0.f), fmaxf(acc3, 0.f) };

    float part[4][5];
    #pragma unroll
    for (int aa = 0; aa < 4; aa++) {
        part[aa][0] = xf[aa] * w_obj[aidv[aa] * 256 + c];
        #pragma unroll
        for (int j = 0; j < 4; j++)
            part[aa][1 + j] = xf[aa] * w_del[(aidv[aa] * 4 + j) * 256 + c];
    }
    const int lane = c & 63, wid = c >> 6;
    #pragma unroll
    for (int o = 32; o > 0; o >>= 1)
        #pragma unroll
        for (int aa = 0; aa < 4; aa++)
            #pragma unroll
            for (int j = 0; j < 5; j++)
                part[aa][j] += __shfl_down(part[aa][j], o);
    if (lane == 0)
        #pragma unroll
        for (int aa = 0; aa < 4; aa++)
            #pragma unroll
            for (int j = 0; j < 5; j++)
                red[aa][j][wid] = part[aa][j];
    __syncthreads();

    if (c < 4 && actv[c]) {
        const int aa = c;
        float logit = red[aa][0][0] + red[aa][0][1] + red[aa][0][2] + red[aa][0][3] + b_obj[aidv[aa]];
        float tgt = isposv[aa] ? 1.f : 0.f;
        float bce = fmaxf(logit, 0.f) - logit * tgt + log1pf(expf(-fabsf(logit)));
        atomicAdd(&lsum[0], bce);
        if (isposv[aa]) {
            float d[4];
            #pragma unroll
            for (int j = 0; j < 4; j++)
                d[j] = red[aa][1 + j][0] + red[aa][1 + j][1] + red[aa][1 + j][2] + red[aa][1 + j][3]
                       + b_del[aidv[aa] * 4 + j];
            int a = av[aa];
            int m = packed[(size_t)img * A_TOTAL + a] & 31;
            const float* s = anchors + (size_t)a * 4;
            const float* t = gt + (size_t)(img * NGT + m) * 4;
            float sw = s[2] - s[0], sh = s[3] - s[1];
            float scx = s[0] + 0.5f * sw, scy = s[1] + 0.5f * sh;
            float tw = t[2] - t[0], th = t[3] - t[1];
            float tcx = t[0] + 0.5f * tw, tcy = t[1] + 0.5f * th;
            float g0 = (tcx - scx) / sw, g1 = (tcy - scy) / sh;
            float g2 = logf(tw / sw),    g3 = logf(th / sh);
            float l1 = fabsf(d[0] - g0) + fabsf(d[1] - g1) + fabsf(d[2] - g2) + fabsf(d[3] - g3);
            atomicAdd(&lsum[1], l1);
        }
    }
    __syncthreads();
    if (c == 0) {
        atomicAdd(&out[0], 0.5f * lsum[0]);
        atomicAdd(&out[1], 0.5f * lsum[1]);
    }
}

extern "C" void kernel_launch(void* const* d_in, const int* in_sizes, int n_in,
                              void* d_out, int out_size, void* d_ws, size_t ws_size,
                              hipStream_t stream) {
    const float* f_p6 = (const float*)d_in[0];
    const float* f_p5 = (const float*)d_in[1];
    const float* f_p4 = (const float*)d_in[2];
    const float* f_p3 = (const float*)d_in[3];
    const float* f_p2 = (const float*)d_in[4];
    const float* anchors = (const float*)d_in[5];
    const float* gt      = (const float*)d_in[6];
    const float* w_in  = (const float*)d_in[7];
    const float* b_in  = (const float*)d_in[8];
    const float* w_obj = (const float*)d_in[9];
    const float* b_obj = (const float*)d_in[10];
    const float* w_del = (const float*)d_in[11];
    const float* b_del = (const float*)d_in[12];

    // workspace layout
    char* ws = (char*)d_ws;
    unsigned int* best          = (unsigned int*)(ws + 0);          // 160 B
    int* pos_total              = (int*)(ws + 160);                 // 8 B
    int* sel_count              = (int*)(ws + 168);                 // 8 B
    int* sel                    = (int*)(ws + 192);                 // 2048 B
    unsigned int* blk_cnt       = (unsigned int*)(ws + 2240);       // 5000 B
    unsigned long long* blk_off = (unsigned long long*)(ws + 7296); // 10000 B
    unsigned char* packed       = (unsigned char*)(ws + 17344);     // 319764 B
    float* lossbuf              = (float*)(ws + 337152);            // 4096 B
    float* xpart                = (float*)(ws + 341248);            // NCH*2*256*256*4 B
    float* pmax                 = (float*)(ws + 341248);            // overlay on xpart
    // pmax (100 KB) is consumed by k_bred before k_conv writes xpart.
    const size_t WS_NEED4 = 341248 + 2u * 4 * 256 * 256 * 4;   // 2438400
    const size_t WS_NEED8 = 341248 + 2u * 8 * 256 * 256 * 4;   // 4535552

    float* out = (float*)d_out;

    if (ws_size >= WS_NEED4) {
        // selection pipeline (no init needed: k_bred/k_final fully write best/out)
        k_bmax<<<dim3(NBLK, 2), 256, 0, stream>>>(anchors, gt, pmax);
        k_bred<<<dim3(NGT, 2), 256, 0, stream>>>(pmax, best);
        k_label<<<dim3(NBLK, 2), 256, 0, stream>>>(anchors, gt, best, packed, blk_cnt);
        k_offsets<<<2, 1024, 0, stream>>>(blk_cnt, blk_off, pos_total, sel_count);
        k_select<<<dim3(NBLK, 2), 256, 0, stream>>>(packed, blk_off, pos_total, sel);
        if (ws_size >= WS_NEED8) {
            k_conv<8><<<dim3(64, 8, 2), 256, 0, stream>>>(f_p6, f_p5, f_p4, f_p3, f_p2,
                                                          w_in, sel, sel_count, xpart);
            k_post<8><<<dim3(256, 2), 256, 0, stream>>>(xpart, anchors, gt, b_in,
                                                        w_obj, b_obj, w_del, b_del,
                                                        packed, sel, sel_count, lossbuf);
        } else {
            k_conv<4><<<dim3(64, 4, 2), 256, 0, stream>>>(f_p6, f_p5, f_p4, f_p3, f_p2,
                                                          w_in, sel, sel_count, xpart);
            k_post<4><<<dim3(256, 2), 256, 0, stream>>>(xpart, anchors, gt, b_in,
                                                        w_obj, b_obj, w_del, b_del,
                                                        packed, sel, sel_count, lossbuf);
        }
        k_final<<<1, 512, 0, stream>>>(lossbuf, sel_count, out);
    } else {
        k_init<<<1, 64, 0, stream>>>(best, out);
        k_best<<<dim3(64, 2), 256, 0, stream>>>(anchors, gt, best);
        k_label<<<dim3(NBLK, 2), 256, 0, stream>>>(anchors, gt, best, packed, blk_cnt);
        k_offsets<<<2, 1024, 0, stream>>>(blk_cnt, blk_off, pos_total, sel_count);
        k_select<<<dim3(NBLK, 2), 256, 0, stream>>>(packed, blk_off, pos_total, sel);
        k_eval<<<128, 256, 0, stream>>>(f_p6, f_p5, f_p4, f_p3, f_p2,
                                        anchors, gt, w_in, b_in, w_obj, b_obj,
                                        w_del, b_del, packed, sel, sel_count, out);
    }
}

// Round 7
// 66.868 us; speedup vs baseline: 14.3598x; 1.1982x over previous
//
#include <hip/hip_runtime.h>
#include <hip/hip_bf16.h>
#include <math.h>

#define A_TOTAL 159882
#define NGT 20
#define NBLK 625   // ceil(A_TOTAL/256)
#define ANB 4      // anchors per conv block

// level geometry: p6(13) p5(25) p4(50) p3(100) p2(200), 3 anchors/pos
// cumulative anchor offsets: 0, 507, 2382, 9882, 39882, 159882

__device__ __forceinline__ float iou_one(float ax1, float ay1, float ax2, float ay2,
                                         float gx1, float gy1, float gx2, float gy2) {
    float a1 = (ax2 - ax1) * (ay2 - ay1);
    float a2 = (gx2 - gx1) * (gy2 - gy1);
    float ltx = fmaxf(ax1, gx1), lty = fmaxf(ay1, gy1);
    float rbx = fminf(ax2, gx2), rby = fminf(ay2, gy2);
    float w = fmaxf(rbx - ltx, 0.f), h = fmaxf(rby - lty, 0.f);
    float inter = w * h;
    return inter / (a1 + a2 - inter);
}

__device__ __forceinline__ void decode_anchor(int a, int& W, int& aid, int& y, int& x, int& lvl) {
    int off;
    if      (a < 507)   { off = 0;     W = 13;  lvl = 0; }
    else if (a < 2382)  { off = 507;   W = 25;  lvl = 1; }
    else if (a < 9882)  { off = 2382;  W = 50;  lvl = 2; }
    else if (a < 39882) { off = 9882;  W = 100; lvl = 3; }
    else                { off = 39882; W = 200; lvl = 4; }
    int rel = a - off;
    aid = rel % 3;
    int pos = rel / 3;
    y = pos / W; x = pos % W;
}

__global__ void k_init(unsigned int* best, float* out) {
    int t = threadIdx.x;
    if (t < 2 * NGT) best[t] = 0u;
    if (t < 2) out[t] = 0.f;
}

// weight repack: wt[k4][co][j] = w_in[co][k4*4+j]  (read-coalesced per row)
__global__ __launch_bounds__(576) void k_wtrans(const float* __restrict__ w_in,
                                                float* __restrict__ wt) {
    const int co = blockIdx.x;      // 256 blocks
    const int k4 = threadIdx.x;     // 576 threads = one float4 each
    float4 v = *(const float4*)(w_in + (size_t)co * 2304 + k4 * 4);
    ((float4*)wt)[(size_t)k4 * 256 + co] = v;
}

// pass 1a: per-block column maxes of the IoU matrix (full grid, no atomics)
__global__ __launch_bounds__(256) void k_bmax(const float* __restrict__ anchors,
                                              const float* __restrict__ gt,
                                              float* __restrict__ pmax) {
    const int img = blockIdx.y;
    __shared__ float sgt[NGT * 4];
    __shared__ float sred[4][NGT];
    const int tid = threadIdx.x;
    if (tid < NGT * 4) sgt[tid] = gt[img * NGT * 4 + tid];
    __syncthreads();
    const int a = blockIdx.x * 256 + tid;
    float4 ab = make_float4(0.f, 0.f, 1.f, 1.f);
    if (a < A_TOTAL) ab = ((const float4*)anchors)[a];
    const int lane = tid & 63, wid = tid >> 6;
    #pragma unroll
    for (int g = 0; g < NGT; g++) {
        float u = (a < A_TOTAL)
                    ? iou_one(ab.x, ab.y, ab.z, ab.w,
                              sgt[g * 4], sgt[g * 4 + 1], sgt[g * 4 + 2], sgt[g * 4 + 3])
                    : 0.f;
        #pragma unroll
        for (int o = 32; o > 0; o >>= 1) u = fmaxf(u, __shfl_down(u, o));
        if (lane == 0) sred[wid][g] = u;
    }
    __syncthreads();
    if (tid < NGT) {
        float u = fmaxf(fmaxf(sred[0][tid], sred[1][tid]),
                        fmaxf(sred[2][tid], sred[3][tid]));
        pmax[((size_t)img * NBLK + blockIdx.x) * NGT + tid] = u;
    }
}

// pass 1b: tree-reduce 625 partials per (img, gt) -> best (plain store)
__global__ void k_bred(const float* __restrict__ pmax, unsigned int* __restrict__ best) {
    const int g = blockIdx.x, img = blockIdx.y;
    const int tid = threadIdx.x;   // 256
    float v = 0.f;
    for (int i = tid; i < NBLK; i += 256)
        v = fmaxf(v, pmax[((size_t)img * NBLK + i) * NGT + g]);
    const int lane = tid & 63, wid = tid >> 6;
    #pragma unroll
    for (int o = 32; o > 0; o >>= 1) v = fmaxf(v, __shfl_down(v, o));
    __shared__ float r[4];
    if (lane == 0) r[wid] = v;
    __syncthreads();
    if (tid == 0)
        best[img * NGT + g] = __float_as_uint(fmaxf(fmaxf(r[0], r[1]), fmaxf(r[2], r[3])));
}

// fallback pass 1 (round-2 proven): register running max + 20 atomics/block
__global__ void k_best(const float* __restrict__ anchors, const float* __restrict__ gt,
                       unsigned int* best) {
    const int img = blockIdx.y;
    __shared__ float sgt[NGT * 4];
    __shared__ float sred[4][NGT];
    const int tid = threadIdx.x;
    if (tid < NGT * 4) sgt[tid] = gt[img * NGT * 4 + tid];
    __syncthreads();
    float vmax[NGT];
    #pragma unroll
    for (int g = 0; g < NGT; g++) vmax[g] = 0.f;
    const int stride = gridDim.x * blockDim.x;
    for (int a = blockIdx.x * blockDim.x + tid; a < A_TOTAL; a += stride) {
        float4 ab = ((const float4*)anchors)[a];
        #pragma unroll
        for (int g = 0; g < NGT; g++) {
            float v = iou_one(ab.x, ab.y, ab.z, ab.w,
                              sgt[g * 4], sgt[g * 4 + 1], sgt[g * 4 + 2], sgt[g * 4 + 3]);
            vmax[g] = fmaxf(vmax[g], v);
        }
    }
    const int lane = tid & 63, wid = tid >> 6;
    #pragma unroll
    for (int g = 0; g < NGT; g++) {
        float v = vmax[g];
        #pragma unroll
        for (int o = 32; o > 0; o >>= 1) v = fmaxf(v, __shfl_down(v, o));
        if (lane == 0) sred[wid][g] = v;
    }
    __syncthreads();
    if (tid < NGT) {
        float v = fmaxf(fmaxf(sred[0][tid], sred[1][tid]),
                        fmaxf(sred[2][tid], sred[3][tid]));
        atomicMax(&best[img * NGT + tid], __float_as_uint(v));
    }
}

// pass 2: labels + matched gt packed into a byte; per-block pos/neg counts
__global__ void k_label(const float* __restrict__ anchors, const float* __restrict__ gt,
                        const unsigned int* __restrict__ best,
                        unsigned char* packed, unsigned int* blk_cnt) {
    const int img = blockIdx.y;
    __shared__ float sgt[NGT * 4];
    __shared__ unsigned int sbest[NGT];
    __shared__ int wp[4], wn[4];
    const int tid = threadIdx.x;
    if (tid < NGT * 4) sgt[tid] = gt[img * NGT * 4 + tid];
    if (tid < NGT) sbest[tid] = best[img * NGT + tid];
    __syncthreads();
    const int a = blockIdx.x * blockDim.x + tid;
    const bool act = a < A_TOTAL;
    int code = 2;
    if (act) {
        float4 ab = ((const float4*)anchors)[a];
        float mval = -1.f; int arg = 0; bool lq = false;
        #pragma unroll
        for (int g = 0; g < NGT; g++) {
            float v = iou_one(ab.x, ab.y, ab.z, ab.w,
                              sgt[g * 4], sgt[g * 4 + 1], sgt[g * 4 + 2], sgt[g * 4 + 3]);
            if (v > mval) { mval = v; arg = g; }
            if (__float_as_uint(v) == sbest[g] && v > 0.f) lq = true;
        }
        if (lq || mval >= 0.7f) code = 1;
        else if (mval < 0.3f)   code = 0;
        packed[(size_t)img * A_TOTAL + a] = (unsigned char)((code << 5) | arg);
    }
    unsigned long long bp = __ballot(act && code == 1);
    unsigned long long bn = __ballot(act && code == 0);
    const int lane = tid & 63, wid = tid >> 6;
    if (lane == 0) { wp[wid] = __popcll(bp); wn[wid] = __popcll(bn); }
    __syncthreads();
    if (tid == 0) {
        unsigned int p = wp[0] + wp[1] + wp[2] + wp[3];
        unsigned int n = wn[0] + wn[1] + wn[2] + wn[3];
        blk_cnt[img * NBLK + blockIdx.x] = (p << 16) | n;
    }
}

// pass 3a: scan 625 block counts per image (shfl two-level scan, 2 barriers)
__global__ void k_offsets(const unsigned int* __restrict__ blk_cnt,
                          unsigned long long* blk_off,
                          int* pos_total, int* sel_count) {
    const int img = blockIdx.x;
    const int t = threadIdx.x;           // 1024 threads
    const int lane = t & 63, wid = t >> 6;
    unsigned long long c = 0ULL;
    if (t < NBLK) {
        unsigned int u = blk_cnt[img * NBLK + t];
        c = ((unsigned long long)(u >> 16) << 32) | (u & 0xFFFFu);
    }
    unsigned long long v = c;
    #pragma unroll
    for (int off = 1; off < 64; off <<= 1) {
        unsigned long long u = __shfl_up(v, off);
        if (lane >= off) v += u;
    }
    __shared__ unsigned long long wsum[16];
    if (lane == 63) wsum[wid] = v;
    __syncthreads();
    if (wid == 0) {
        unsigned long long w = (lane < 16) ? wsum[lane] : 0ULL;
        #pragma unroll
        for (int off = 1; off < 16; off <<= 1) {
            unsigned long long u = __shfl_up(w, off);
            if (lane >= off) w += u;
        }
        if (lane < 16) wsum[lane] = w;   // inclusive wave prefix
    }
    __syncthreads();
    unsigned long long excl = v - c + (wid > 0 ? wsum[wid - 1] : 0ULL);
    if (t < NBLK) blk_off[img * NBLK + t] = excl;
    if (t == 1023) {
        unsigned long long tot = wsum[15];
        int tp = (int)(tot >> 32), tn = (int)(tot & 0xFFFFFFFFu);
        int npos = min(tp, 128);
        int nneg = min(tn, 256 - npos);
        pos_total[img] = tp;
        sel_count[img] = npos + nneg;
    }
}

// pass 3b: write selected anchors to deterministic slots (no atomics)
__global__ void k_select(const unsigned char* __restrict__ packed,
                         const unsigned long long* __restrict__ blk_off,
                         const int* __restrict__ pos_total,
                         int* sel) {
    const int img = blockIdx.y;
    const int t = threadIdx.x;
    const int a = blockIdx.x * 256 + t;
    const bool act = a < A_TOTAL;
    int code = 2;
    if (act) code = packed[(size_t)img * A_TOTAL + a] >> 5;
    const bool isp = act && code == 1;
    const bool isn = act && code == 0;
    unsigned long long bp = __ballot(isp);
    unsigned long long bn = __ballot(isn);
    const int lane = t & 63, wid = t >> 6;
    __shared__ int wtp[4], wtn[4];
    if (lane == 0) { wtp[wid] = __popcll(bp); wtn[wid] = __popcll(bn); }
    __syncthreads();
    const unsigned long long mlt = (1ULL << lane) - 1ULL;
    int rp = __popcll(bp & mlt);
    int rn = __popcll(bn & mlt);
    for (int w = 0; w < 4; w++) {
        if (w < wid) { rp += wtp[w]; rn += wtn[w]; }
    }
    unsigned long long bo = blk_off[img * NBLK + blockIdx.x];
    const int base_p = (int)(bo >> 32), base_n = (int)(bo & 0xFFFFFFFFu);
    const int npos = min(pos_total[img], 128);
    const int capn = 256 - npos;
    if (isp) {
        int r = base_p + rp;
        if (r < npos) sel[img * 256 + r] = a | (1 << 30);
    }
    if (isn) {
        int r = base_n + rn;
        if (r < capn) sel[img * 256 + npos + r] = a;
    }
}

// shared patch-staging for conv kernels
template <int TRM>
__device__ __forceinline__ void stage_patches(
    const float* __restrict__ f0, const float* __restrict__ f1,
    const float* __restrict__ f2, const float* __restrict__ f3,
    const float* __restrict__ f4,
    const int* __restrict__ sel, int nsel, int img, int chunk, int slot0,
    float (&patch)[ANB][TRM],
    int (&s_W)[ANB], int (&s_y)[ANB], int (&s_x)[ANB], int (&s_act)[ANB],
    const float* (&s_fm)[ANB]) {
    constexpr int CIP = TRM / 9;
    const int tid = threadIdx.x;
    if (tid < ANB) {
        int slot = slot0 + tid;
        bool act = slot < nsel;
        int e = act ? sel[img * 256 + slot] : 0;
        int a = e & 0x3FFFFFFF;
        int W, aid, y, x, lvl;
        decode_anchor(a, W, aid, y, x, lvl);
        s_W[tid] = W; s_y[tid] = y; s_x[tid] = x; s_act[tid] = act ? 1 : 0;
        s_fm[tid] = (lvl == 0 ? f0 : lvl == 1 ? f1 : lvl == 2 ? f2 : lvl == 3 ? f3 : f4);
    }
    __syncthreads();
    for (int p = tid; p < ANB * TRM; p += 256) {
        int aa = p / TRM;
        int idx = p - aa * TRM;
        int cil = idx / 9;
        int r = idx - cil * 9;
        int ky = r / 3, kx = r - ky * 3;
        int W = s_W[aa];
        int yy = s_y[aa] + ky - 1, xx = s_x[aa] + kx - 1;
        float v = 0.f;
        if (s_act[aa] && yy >= 0 && yy < W && xx >= 0 && xx < W) {
            const float* fm = s_fm[aa];
            int ci = chunk * CIP + cil;
            v = fm[(((size_t)img * 256 + ci) * W + yy) * W + xx];
        }
        patch[aa][idx] = v;
    }
    __syncthreads();
}

// pass 4a (transposed weights): coalesced wt reads + LDS broadcast patches
template <int NCH>
__global__ __launch_bounds__(256) void k_convT(
    const float* __restrict__ f0, const float* __restrict__ f1,
    const float* __restrict__ f2, const float* __restrict__ f3,
    const float* __restrict__ f4,
    const float* __restrict__ wt,
    const int* __restrict__ sel, const int* __restrict__ sel_count,
    float* __restrict__ xpart) {
    constexpr int CIP = 256 / NCH;
    constexpr int TRM = CIP * 9;
    const int img = blockIdx.z;
    const int chunk = blockIdx.y;
    const int slot0 = blockIdx.x * ANB;
    const int nsel = sel_count[img];
    if (slot0 >= nsel) return;

    __shared__ __align__(16) float patch[ANB][TRM];
    __shared__ int s_W[ANB], s_y[ANB], s_x[ANB], s_act[ANB];
    __shared__ const float* s_fm[ANB];
    stage_patches<TRM>(f0, f1, f2, f3, f4, sel, nsel, img, chunk, slot0,
                       patch, s_W, s_y, s_x, s_act, s_fm);

    const int c = threadIdx.x;
    const float4* wt4 = (const float4*)wt + (size_t)(chunk * (TRM / 4)) * 256 + c;
    const float4* p0 = (const float4*)patch[0];
    const float4* p1 = (const float4*)patch[1];
    const float4* p2 = (const float4*)patch[2];
    const float4* p3 = (const float4*)patch[3];
    float acc0 = 0.f, acc1 = 0.f, acc2 = 0.f, acc3 = 0.f;
    #pragma unroll 8
    for (int i = 0; i < TRM / 4; i++) {
        float4 w = wt4[(size_t)i * 256];      // 1KB contiguous per wave
        float4 q;
        q = p0[i]; acc0 += w.x * q.x + w.y * q.y + w.z * q.z + w.w * q.w;
        q = p1[i]; acc1 += w.x * q.x + w.y * q.y + w.z * q.z + w.w * q.w;
        q = p2[i]; acc2 += w.x * q.x + w.y * q.y + w.z * q.z + w.w * q.w;
        q = p3[i]; acc3 += w.x * q.x + w.y * q.y + w.z * q.z + w.w * q.w;
    }
    float acc[ANB] = {acc0, acc1, acc2, acc3};
    #pragma unroll
    for (int aa = 0; aa < ANB; aa++) {
        int slot = slot0 + aa;
        if (slot < nsel)
            xpart[(((size_t)img * NCH + chunk) * 256 + slot) * 256 + c] = acc[aa];
    }
}

// pass 4a (raw weights, round-6 proven fallback)
template <int NCH>
__global__ __launch_bounds__(256) void k_conv(
    const float* __restrict__ f0, const float* __restrict__ f1,
    const float* __restrict__ f2, const float* __restrict__ f3,
    const float* __restrict__ f4,
    const float* __restrict__ w_in,
    const int* __restrict__ sel, const int* __restrict__ sel_count,
    float* __restrict__ xpart) {
    constexpr int CIP = 256 / NCH;
    constexpr int TRM = CIP * 9;
    const int img = blockIdx.z;
    const int chunk = blockIdx.y;
    const int slot0 = blockIdx.x * ANB;
    const int nsel = sel_count[img];
    if (slot0 >= nsel) return;

    __shared__ __align__(16) float patch[ANB][TRM];
    __shared__ int s_W[ANB], s_y[ANB], s_x[ANB], s_act[ANB];
    __shared__ const float* s_fm[ANB];
    stage_patches<TRM>(f0, f1, f2, f3, f4, sel, nsel, img, chunk, slot0,
                       patch, s_W, s_y, s_x, s_act, s_fm);

    const int c = threadIdx.x;
    const float4* wr = (const float4*)(w_in + (size_t)c * 2304 + chunk * TRM);
    const float4* p0 = (const float4*)patch[0];
    const float4* p1 = (const float4*)patch[1];
    const float4* p2 = (const float4*)patch[2];
    const float4* p3 = (const float4*)patch[3];
    float acc0 = 0.f, acc1 = 0.f, acc2 = 0.f, acc3 = 0.f;
    #pragma unroll 8
    for (int i = 0; i < TRM / 4; i++) {
        float4 w = wr[i];
        float4 q;
        q = p0[i]; acc0 += w.x * q.x + w.y * q.y + w.z * q.z + w.w * q.w;
        q = p1[i]; acc1 += w.x * q.x + w.y * q.y + w.z * q.z + w.w * q.w;
        q = p2[i]; acc2 += w.x * q.x + w.y * q.y + w.z * q.z + w.w * q.w;
        q = p3[i]; acc3 += w.x * q.x + w.y * q.y + w.z * q.z + w.w * q.w;
    }
    float acc[ANB] = {acc0, acc1, acc2, acc3};
    #pragma unroll
    for (int aa = 0; aa < ANB; aa++) {
        int slot = slot0 + aa;
        if (slot < nsel)
            xpart[(((size_t)img * NCH + chunk) * 256 + slot) * 256 + c] = acc[aa];
    }
}

// pass 4b: reduce chunks + bias + relu, 5 block-dots, per-anchor losses
template <int NCH>
__global__ __launch_bounds__(256) void k_post(
    const float* __restrict__ xpart,
    const float* __restrict__ anchors, const float* __restrict__ gt,
    const float* __restrict__ b_in,
    const float* __restrict__ w_obj, const float* __restrict__ b_obj,
    const float* __restrict__ w_del, const float* __restrict__ b_del,
    const unsigned char* __restrict__ packed,
    const int* __restrict__ sel, const int* __restrict__ sel_count,
    float* __restrict__ lossbuf) {
    const int img = blockIdx.y;
    const int slot = blockIdx.x;
    const int nsel = sel_count[img];
    if (slot >= nsel) return;
    const int e = sel[img * 256 + slot];
    const int is_pos = (e >> 30) & 1;
    const int a = e & 0x3FFFFFFF;
    int W, aid, y, x, lvl;
    decode_anchor(a, W, aid, y, x, lvl);

    const int c = threadIdx.x;
    float s = b_in[c];
    #pragma unroll
    for (int ch = 0; ch < NCH; ch++)
        s += xpart[(((size_t)img * NCH + ch) * 256 + slot) * 256 + c];
    float xf = fmaxf(s, 0.f);

    float part[5];
    part[0] = xf * w_obj[aid * 256 + c];
    #pragma unroll
    for (int j = 0; j < 4; j++) part[1 + j] = xf * w_del[(aid * 4 + j) * 256 + c];
    const int lane = c & 63, wid = c >> 6;
    __shared__ float red[5][4];
    #pragma unroll
    for (int o = 32; o > 0; o >>= 1)
        #pragma unroll
        for (int j = 0; j < 5; j++) part[j] += __shfl_down(part[j], o);
    if (lane == 0)
        #pragma unroll
        for (int j = 0; j < 5; j++) red[j][wid] = part[j];
    __syncthreads();

    if (c == 0) {
        float logit = red[0][0] + red[0][1] + red[0][2] + red[0][3] + b_obj[aid];
        float tgt = is_pos ? 1.f : 0.f;
        float bce = fmaxf(logit, 0.f) - logit * tgt + log1pf(expf(-fabsf(logit)));
        float l1 = 0.f;
        if (is_pos) {
            float d[4];
            #pragma unroll
            for (int j = 0; j < 4; j++)
                d[j] = red[1 + j][0] + red[1 + j][1] + red[1 + j][2] + red[1 + j][3] + b_del[aid * 4 + j];
            int m = packed[(size_t)img * A_TOTAL + a] & 31;
            const float* sp = anchors + (size_t)a * 4;
            const float* t = gt + (size_t)(img * NGT + m) * 4;
            float sw = sp[2] - sp[0], sh = sp[3] - sp[1];
            float scx = sp[0] + 0.5f * sw, scy = sp[1] + 0.5f * sh;
            float tw = t[2] - t[0], th = t[3] - t[1];
            float tcx = t[0] + 0.5f * tw, tcy = t[1] + 0.5f * th;
            float g0 = (tcx - scx) / sw, g1 = (tcy - scy) / sh;
            float g2 = logf(tw / sw),    g3 = logf(th / sh);
            l1 = fabsf(d[0] - g0) + fabsf(d[1] - g1) + fabsf(d[2] - g2) + fabsf(d[3] - g3);
        }
        lossbuf[(img * 256 + slot) * 2 + 0] = bce;
        lossbuf[(img * 256 + slot) * 2 + 1] = l1;
    }
}

// pass 5: deterministic tree-sum of per-anchor losses -> out[2]
__global__ void k_final(const float* __restrict__ lossbuf,
                        const int* __restrict__ sel_count,
                        float* __restrict__ out) {
    const int t = threadIdx.x;      // 512 threads
    const int img = t >> 8, slot = t & 255;
    float bce = 0.f, l1 = 0.f;
    if (slot < sel_count[img]) {
        bce = lossbuf[t * 2 + 0];
        l1  = lossbuf[t * 2 + 1];
    }
    const int lane = t & 63, wid = t >> 6;
    #pragma unroll
    for (int o = 32; o > 0; o >>= 1) {
        bce += __shfl_down(bce, o);
        l1  += __shfl_down(l1, o);
    }
    __shared__ float rb[8], rl[8];
    if (lane == 0) { rb[wid] = bce; rl[wid] = l1; }
    __syncthreads();
    if (t == 0) {
        float sb = 0.f, sl = 0.f;
        #pragma unroll
        for (int w = 0; w < 8; w++) { sb += rb[w]; sl += rl[w]; }
        out[0] = 0.5f * sb;
        out[1] = 0.5f * sl;
    }
}

// fallback monolithic eval (round-3 proven) if workspace is tiny
__global__ __launch_bounds__(256) void k_eval(
    const float* __restrict__ f0, const float* __restrict__ f1,
    const float* __restrict__ f2, const float* __restrict__ f3,
    const float* __restrict__ f4,
    const float* __restrict__ anchors, const float* __restrict__ gt,
    const float* __restrict__ w_in, const float* __restrict__ b_in,
    const float* __restrict__ w_obj, const float* __restrict__ b_obj,
    const float* __restrict__ w_del, const float* __restrict__ b_del,
    const unsigned char* __restrict__ packed,
    const int* __restrict__ sel, const int* __restrict__ sel_count,
    float* out) {
    const int img = blockIdx.x >> 6;
    const int slot0 = (blockIdx.x & 63) * 4;
    const int nsel = sel_count[img];
    if (slot0 >= nsel) return;

    __shared__ __align__(16) float patch[4][2304];
    __shared__ float red[4][5][4];
    __shared__ float lsum[2];
    const int c = threadIdx.x;
    if (c < 2) lsum[c] = 0.f;

    bool actv[4]; int av[4], aidv[4], isposv[4];
    #pragma unroll
    for (int aa = 0; aa < 4; aa++) {
        int slot = slot0 + aa;
        bool act = slot < nsel;
        actv[aa] = act;
        int e = act ? sel[img * 256 + slot] : 0;
        isposv[aa] = (e >> 30) & 1;
        int a = e & 0x3FFFFFFF;
        av[aa] = a;
        int W, aid, y, x, lvl;
        decode_anchor(a, W, aid, y, x, lvl);
        aidv[aa] = aid;
        const float* fm = lvl == 0 ? f0 : lvl == 1 ? f1 : lvl == 2 ? f2 : lvl == 3 ? f3 : f4;
        const float* ch = fm + ((size_t)img * 256 + c) * W * W;
        #pragma unroll
        for (int ky = 0; ky < 3; ky++)
            #pragma unroll
            for (int kx = 0; kx < 3; kx++) {
                int yy = y + ky - 1, xx = x + kx - 1;
                float v = (act && yy >= 0 && yy < W && xx >= 0 && xx < W) ? ch[yy * W + xx] : 0.f;
                patch[aa][c * 9 + ky * 3 + kx] = v;
            }
    }
    __syncthreads();

    const float bi = b_in[c];
    float acc0 = bi, acc1 = bi, acc2 = bi, acc3 = bi;
    const float4* wr = (const float4*)(w_in + (size_t)c * 2304);
    const float4* p0 = (const float4*)patch[0];
    const float4* p1 = (const float4*)patch[1];
    const float4* p2 = (const float4*)patch[2];
    const float4* p3 = (const float4*)patch[3];
    #pragma unroll 4
    for (int i = 0; i < 576; i++) {
        float4 w = wr[i];
        float4 q;
        q = p0[i]; acc0 += w.x * q.x + w.y * q.y + w.z * q.z + w.w * q.w;
        q = p1[i]; acc1 += w.x * q.x + w.y * q.y + w.z * q.z + w.w * q.w;
        q = p2[i]; acc2 += w.x * q.x + w.y * q.y + w.z * q.z + w.w * q.w;
        q = p3[i]; acc3 += w.x * q.x + w.y * q.y + w.z * q.z + w.w * q.w;
    }
    float xf[4] = { fmaxf(acc0, 0.f), fmaxf(acc1, 0.f), fmaxf(acc2, 0.f), fmaxf(acc3, 0.f) };

    float part[4][5];
    #pragma unroll
    for (int aa = 0; aa < 4; aa++) {
        part[aa][0] = xf[aa] * w_obj[aidv[aa] * 256 + c];
        #pragma unroll
        for (int j = 0; j < 4; j++)
            part[aa][1 + j] = xf[aa] * w_del[(aidv[aa] * 4 + j) * 256 + c];
    }
    const int lane = c & 63, wid = c >> 6;
    #pragma unroll
    for (int o = 32; o > 0; o >>= 1)
        #pragma unroll
        for (int aa = 0; aa < 4; aa++)
            #pragma unroll
            for (int j = 0; j < 5; j++)
                part[aa][j] += __shfl_down(part[aa][j], o);
    if (lane == 0)
        #pragma unroll
        for (int aa = 0; aa < 4; aa++)
            #pragma unroll
            for (int j = 0; j < 5; j++)
                red[aa][j][wid] = part[aa][j];
    __syncthreads();

    if (c < 4 && actv[c]) {
        const int aa = c;
        float logit = red[aa][0][0] + red[aa][0][1] + red[aa][0][2] + red[aa][0][3] + b_obj[aidv[aa]];
        float tgt = isposv[aa] ? 1.f : 0.f;
        float bce = fmaxf(logit, 0.f) - logit * tgt + log1pf(expf(-fabsf(logit)));
        atomicAdd(&lsum[0], bce);
        if (isposv[aa]) {
            float d[4];
            #pragma unroll
            for (int j = 0; j < 4; j++)
                d[j] = red[aa][1 + j][0] + red[aa][1 + j][1] + red[aa][1 + j][2] + red[aa][1 + j][3]
                       + b_del[aidv[aa] * 4 + j];
            int a = av[aa];
            int m = packed[(size_t)img * A_TOTAL + a] & 31;
            const float* s = anchors + (size_t)a * 4;
            const float* t = gt + (size_t)(img * NGT + m) * 4;
            float sw = s[2] - s[0], sh = s[3] - s[1];
            float scx = s[0] + 0.5f * sw, scy = s[1] + 0.5f * sh;
            float tw = t[2] - t[0], th = t[3] - t[1];
            float tcx = t[0] + 0.5f * tw, tcy = t[1] + 0.5f * th;
            float g0 = (tcx - scx) / sw, g1 = (tcy - scy) / sh;
            float g2 = logf(tw / sw),    g3 = logf(th / sh);
            float l1 = fabsf(d[0] - g0) + fabsf(d[1] - g1) + fabsf(d[2] - g2) + fabsf(d[3] - g3);
            atomicAdd(&lsum[1], l1);
        }
    }
    __syncthreads();
    if (c == 0) {
        atomicAdd(&out[0], 0.5f * lsum[0]);
        atomicAdd(&out[1], 0.5f * lsum[1]);
    }
}

extern "C" void kernel_launch(void* const* d_in, const int* in_sizes, int n_in,
                              void* d_out, int out_size, void* d_ws, size_t ws_size,
                              hipStream_t stream) {
    const float* f_p6 = (const float*)d_in[0];
    const float* f_p5 = (const float*)d_in[1];
    const float* f_p4 = (const float*)d_in[2];
    const float* f_p3 = (const float*)d_in[3];
    const float* f_p2 = (const float*)d_in[4];
    const float* anchors = (const float*)d_in[5];
    const float* gt      = (const float*)d_in[6];
    const float* w_in  = (const float*)d_in[7];
    const float* b_in  = (const float*)d_in[8];
    const float* w_obj = (const float*)d_in[9];
    const float* b_obj = (const float*)d_in[10];
    const float* w_del = (const float*)d_in[11];
    const float* b_del = (const float*)d_in[12];

    // workspace layout
    char* ws = (char*)d_ws;
    unsigned int* best          = (unsigned int*)(ws + 0);          // 160 B
    int* pos_total              = (int*)(ws + 160);                 // 8 B
    int* sel_count              = (int*)(ws + 168);                 // 8 B
    int* sel                    = (int*)(ws + 192);                 // 2048 B
    unsigned int* blk_cnt       = (unsigned int*)(ws + 2240);       // 5000 B
    unsigned long long* blk_off = (unsigned long long*)(ws + 7296); // 10000 B
    unsigned char* packed       = (unsigned char*)(ws + 17344);     // 319764 B
    float* lossbuf              = (float*)(ws + 337152);            // 4096 B
    float* xpart                = (float*)(ws + 341248);            // NCH*2*256*256*4 B
    float* pmax                 = (float*)(ws + 341248);            // overlay on xpart
    float* wt                   = (float*)(ws + 341248 + 8u*2*256*256*4); // 2359296 B
    const size_t WS_NEED4  = 341248 + 2u * 4 * 256 * 256 * 4;   // 2438400
    const size_t WS_NEED8  = 341248 + 2u * 8 * 256 * 256 * 4;   // 4535552
    const size_t WS_NEEDWT = WS_NEED8 + 2359296;                // 6894848

    float* out = (float*)d_out;

    if (ws_size >= WS_NEED4) {
        if (ws_size >= WS_NEEDWT)
            k_wtrans<<<256, 576, 0, stream>>>(w_in, wt);
        k_bmax<<<dim3(NBLK, 2), 256, 0, stream>>>(anchors, gt, pmax);
        k_bred<<<dim3(NGT, 2), 256, 0, stream>>>(pmax, best);
        k_label<<<dim3(NBLK, 2), 256, 0, stream>>>(anchors, gt, best, packed, blk_cnt);
        k_offsets<<<2, 1024, 0, stream>>>(blk_cnt, blk_off, pos_total, sel_count);
        k_select<<<dim3(NBLK, 2), 256, 0, stream>>>(packed, blk_off, pos_total, sel);
        if (ws_size >= WS_NEEDWT) {
            k_convT<8><<<dim3(64, 8, 2), 256, 0, stream>>>(f_p6, f_p5, f_p4, f_p3, f_p2,
                                                           wt, sel, sel_count, xpart);
            k_post<8><<<dim3(256, 2), 256, 0, stream>>>(xpart, anchors, gt, b_in,
                                                        w_obj, b_obj, w_del, b_del,
                                                        packed, sel, sel_count, lossbuf);
        } else if (ws_size >= WS_NEED8) {
            k_conv<8><<<dim3(64, 8, 2), 256, 0, stream>>>(f_p6, f_p5, f_p4, f_p3, f_p2,
                                                          w_in, sel, sel_count, xpart);
            k_post<8><<<dim3(256, 2), 256, 0, stream>>>(xpart, anchors, gt, b_in,
                                                        w_obj, b_obj, w_del, b_del,
                                                        packed, sel, sel_count, lossbuf);
        } else {
            k_conv<4><<<dim3(64, 4, 2), 256, 0, stream>>>(f_p6, f_p5, f_p4, f_p3, f_p2,
                                                          w_in, sel, sel_count, xpart);
            k_post<4><<<dim3(256, 2), 256, 0, stream>>>(xpart, anchors, gt, b_in,
                                                        w_obj, b_obj, w_del, b_del,
                                                        packed, sel, sel_count, lossbuf);
        }
        k_final<<<1, 512, 0, stream>>>(lossbuf, sel_count, out);
    } else {
        k_init<<<1, 64, 0, stream>>>(best, out);
        k_best<<<dim3(64, 2), 256, 0, stream>>>(anchors, gt, best);
        k_label<<<dim3(NBLK, 2), 256, 0, stream>>>(anchors, gt, best, packed, blk_cnt);
        k_offsets<<<2, 1024, 0, stream>>>(blk_cnt, blk_off, pos_total, sel_count);
        k_select<<<dim3(NBLK, 2), 256, 0, stream>>>(packed, blk_off, pos_total, sel);
        k_eval<<<128, 256, 0, stream>>>(f_p6, f_p5, f_p4, f_p3, f_p2,
                                        anchors, gt, w_in, b_in, w_obj, b_obj,
                                        w_del, b_del, packed, sel, sel_count, out);
    }
}